// Round 3
// baseline (247.947 us; speedup 1.0000x reference)
//
#include <hip/hip_runtime.h>
#include <cstddef>

#define EPSF 1e-6f

constexpr int D   = 1024;
constexpr int Bv  = 2;
constexpr int S   = 2048;
constexpr int M   = Bv * S;    // 4096
constexpr int CH  = 256;       // chunk
constexpr int NCH = S / CH;    // 8

constexpr int TSZ  = 128 * 32; // 128-row LDS tile (elems, 8 KB)
constexpr int TA64 = 64 * 32;  // 64-row LDS tile (elems, 4 KB)

typedef __attribute__((ext_vector_type(8))) short short8;   // 8 bf16
typedef __attribute__((ext_vector_type(4))) float floatx4;  // 4 fp32

__device__ __forceinline__ float elu1(float x) { return x > 0.f ? x + 1.f : __expf(x); }
__device__ __forceinline__ float sigmoidf_(float x) { return 1.f / (1.f + __expf(-x)); }
__device__ __forceinline__ unsigned short f2bf(float x) {
    unsigned u = __float_as_uint(x);
    return (unsigned short)((u + 0x7fffu + ((u >> 16) & 1u)) >> 16);
}
__device__ __forceinline__ float bf2f(unsigned short h) {
    return __uint_as_float(((unsigned)h) << 16);
}
__device__ __forceinline__ float wave_reduce(float x) {
#pragma unroll
    for (int off = 32; off > 0; off >>= 1) x += __shfl_down(x, off);
    return x;
}

// async global->LDS, 16B per lane (dest = wave-uniform base + lane*16)
__device__ __forceinline__ void gl_lds16(const unsigned short* g, unsigned short* l) {
    __builtin_amdgcn_global_load_lds(
        (const __attribute__((address_space(1))) void*)g,
        (__attribute__((address_space(3))) void*)l, 16, 0, 0);
}

// ---- XOR-swizzled staging (both-sides, LDS dest linear; verified r2: conflicts->0) ----
// Tile [R][32] bf16 (64B rows): physical 16B-chunk p of row r holds logical
// chunk c = p ^ ((r>>1)&3).

// stage a 128x32 bf16 tile into LDS row-major [128][32]  (2 loads/thread)
__device__ __forceinline__ void stage128x32(const unsigned short* g, int stride,
                                            unsigned short* lds, int wave, int lane) {
    const int t   = (wave << 6) + lane;
    const int row = t >> 2;
    const int cb  = (((t & 3) ^ ((row >> 1) & 3)) << 3);   // pre-swizzled source chunk
    unsigned short* l0 = lds + (wave << 9);
    gl_lds16(g + (size_t)row * stride + cb, l0);
    gl_lds16(g + (size_t)(row + 64) * stride + cb, l0 + 2048);  // (row+64)>>1 &3 unchanged
}

// stage a 64x32 bf16 tile into LDS row-major [64][32]  (1 load/thread)
__device__ __forceinline__ void stage64x32(const unsigned short* g, int stride,
                                           unsigned short* lds, int wave, int lane) {
    const int t   = (wave << 6) + lane;
    const int row = t >> 2;
    const int cb  = (((t & 3) ^ ((row >> 1) & 3)) << 3);
    gl_lds16(g + (size_t)row * stride + cb, lds + (wave << 9));
}

// 16 MFMAs, 128x128 tile, wave quadrant (wm,wn in {0,64})
__device__ __forceinline__ void mfma_step(const unsigned short* As, const unsigned short* Bs,
                                          int wm, int wn, int fr, int g, floatx4 acc[4][4]) {
    const int off = ((g ^ ((fr >> 1) & 3)) << 3);
    short8 af[4], bf[4];
#pragma unroll
    for (int i = 0; i < 4; ++i) af[i] = *(const short8*)&As[(wm + i * 16 + fr) * 32 + off];
#pragma unroll
    for (int j = 0; j < 4; ++j) bf[j] = *(const short8*)&Bs[(wn + j * 16 + fr) * 32 + off];
#pragma unroll
    for (int i = 0; i < 4; ++i)
#pragma unroll
        for (int j = 0; j < 4; ++j)
            acc[i][j] = __builtin_amdgcn_mfma_f32_16x16x32_bf16(af[i], bf[j], acc[i][j], 0, 0, 0);
}

// 8 MFMAs + 2 ones-MFMAs (rowsum), 64x128 tile (wm in {0,32}, wn in {0,64})
__device__ __forceinline__ void mfma_step64d(const unsigned short* As, const unsigned short* Bs,
                                             int wm, int wn, int fr, int g,
                                             floatx4 acc[2][4], floatx4 accd[2], short8 bones) {
    const int off = ((g ^ ((fr >> 1) & 3)) << 3);
    short8 af[2], bf[4];
#pragma unroll
    for (int i = 0; i < 2; ++i) af[i] = *(const short8*)&As[(wm + i * 16 + fr) * 32 + off];
#pragma unroll
    for (int j = 0; j < 4; ++j) bf[j] = *(const short8*)&Bs[(wn + j * 16 + fr) * 32 + off];
#pragma unroll
    for (int i = 0; i < 2; ++i) {
#pragma unroll
        for (int j = 0; j < 4; ++j)
            acc[i][j] = __builtin_amdgcn_mfma_f32_16x16x32_bf16(af[i], bf[j], acc[i][j], 0, 0, 0);
        accd[i] = __builtin_amdgcn_mfma_f32_16x16x32_bf16(af[i], bones, accd[i], 0, 0, 0);
    }
}

// 8 MFMAs, 64x128 tile (no rowsum)
__device__ __forceinline__ void mfma_step64(const unsigned short* As, const unsigned short* Bs,
                                            int wm, int wn, int fr, int g, floatx4 acc[2][4]) {
    const int off = ((g ^ ((fr >> 1) & 3)) << 3);
    short8 af[2], bf[4];
#pragma unroll
    for (int i = 0; i < 2; ++i) af[i] = *(const short8*)&As[(wm + i * 16 + fr) * 32 + off];
#pragma unroll
    for (int j = 0; j < 4; ++j) bf[j] = *(const short8*)&Bs[(wn + j * 16 + fr) * 32 + off];
#pragma unroll
    for (int i = 0; i < 2; ++i)
#pragma unroll
        for (int j = 0; j < 4; ++j)
            acc[i][j] = __builtin_amdgcn_mfma_f32_16x16x32_bf16(af[i], bf[j], acc[i][j], 0, 0, 0);
}

// Double-buffered K-loop, 128x128 tile.
__device__ __forceinline__ void gemm_loop_db(const unsigned short* Ag, int strideA,
                                             const unsigned short* Bg, int strideB, int Kk,
                                             unsigned short* As, unsigned short* Bs,
                                             int wave, int lane, int wm, int wn, int fr, int g,
                                             floatx4 acc[4][4]) {
    __syncthreads();
    stage128x32(Ag, strideA, As, wave, lane);
    stage128x32(Bg, strideB, Bs, wave, lane);
    int buf = 0;
    for (int k0 = 32; k0 < Kk; k0 += 32) {
        __syncthreads();
        const int nb = buf ^ 1;
        stage128x32(Ag + k0, strideA, As + nb * TSZ, wave, lane);
        stage128x32(Bg + k0, strideB, Bs + nb * TSZ, wave, lane);
        mfma_step(As + buf * TSZ, Bs + buf * TSZ, wm, wn, fr, g, acc);
        buf = nb;
    }
    __syncthreads();
    mfma_step(As + buf * TSZ, Bs + buf * TSZ, wm, wn, fr, g, acc);
}

// Double-buffered K-loop, 64x128 tile, with in-register rowsum (den)
__device__ __forceinline__ void gemm_loop_db64d(const unsigned short* Ag, int strideA,
                                                const unsigned short* Bg, int strideB, int Kk,
                                                unsigned short* As, unsigned short* Bs,
                                                int wave, int lane, int wm, int wn, int fr, int g,
                                                floatx4 acc[2][4], floatx4 accd[2], short8 bones) {
    __syncthreads();
    stage64x32(Ag, strideA, As, wave, lane);
    stage128x32(Bg, strideB, Bs, wave, lane);
    int buf = 0;
    for (int k0 = 32; k0 < Kk; k0 += 32) {
        __syncthreads();
        const int nb = buf ^ 1;
        stage64x32(Ag + k0, strideA, As + nb * TA64, wave, lane);
        stage128x32(Bg + k0, strideB, Bs + nb * TSZ, wave, lane);
        mfma_step64d(As + buf * TA64, Bs + buf * TSZ, wm, wn, fr, g, acc, accd, bones);
        buf = nb;
    }
    __syncthreads();
    mfma_step64d(As + buf * TA64, Bs + buf * TSZ, wm, wn, fr, g, acc, accd, bones);
}

// Double-buffered K-loop, 64x128 tile (plain)
__device__ __forceinline__ void gemm_loop_db64(const unsigned short* Ag, int strideA,
                                               const unsigned short* Bg, int strideB, int Kk,
                                               unsigned short* As, unsigned short* Bs,
                                               int wave, int lane, int wm, int wn, int fr, int g,
                                               floatx4 acc[2][4]) {
    __syncthreads();
    stage64x32(Ag, strideA, As, wave, lane);
    stage128x32(Bg, strideB, Bs, wave, lane);
    int buf = 0;
    for (int k0 = 32; k0 < Kk; k0 += 32) {
        __syncthreads();
        const int nb = buf ^ 1;
        stage64x32(Ag + k0, strideA, As + nb * TA64, wave, lane);
        stage128x32(Bg + k0, strideB, Bs + nb * TSZ, wave, lane);
        mfma_step64(As + buf * TA64, Bs + buf * TSZ, wm, wn, fr, g, acc);
        buf = nb;
    }
    __syncthreads();
    mfma_step64(As + buf * TA64, Bs + buf * TSZ, wm, wn, fr, g, acc);
}

// ---------------- prep: cvt h + cvt 4 weights + transpose memory ----------------
__global__ __launch_bounds__(256) void prep(const float* __restrict__ h,
                                            const float* __restrict__ w_q, const float* __restrict__ w_k,
                                            const float* __restrict__ w_v, const float* __restrict__ w_o,
                                            const float* __restrict__ memory,
                                            unsigned short* __restrict__ h_b,
                                            unsigned short* __restrict__ wq_b, unsigned short* __restrict__ wk_b,
                                            unsigned short* __restrict__ wv_b, unsigned short* __restrict__ wo_b,
                                            unsigned short* __restrict__ memT)
{
    __shared__ unsigned short T[64][72];
    const int id = blockIdx.x, tid = threadIdx.x;
    if (id < 4096) {
        const size_t i = ((size_t)id * 256 + tid) * 4;
        float4 v = *(const float4*)(h + i);
        ushort4 o; o.x = f2bf(v.x); o.y = f2bf(v.y); o.z = f2bf(v.z); o.w = f2bf(v.w);
        *(ushort4*)(h_b + i) = o;
    } else if (id < 8192) {
        const int t = id - 4096, which = t >> 10;
        const float* in = (which == 0) ? w_q : (which == 1) ? w_k : (which == 2) ? w_v : w_o;
        unsigned short* out = (which == 0) ? wq_b : (which == 1) ? wk_b : (which == 2) ? wv_b : wo_b;
        const size_t i = ((size_t)(t & 1023) * 256 + tid) * 4;
        float4 v = *(const float4*)(in + i);
        ushort4 o; o.x = f2bf(v.x); o.y = f2bf(v.y); o.z = f2bf(v.z); o.w = f2bf(v.w);
        *(ushort4*)(out + i) = o;
    } else {
        const int t = id - 8192;
        const int d0 = (t >> 4) * 64, e0 = (t & 15) * 64;
        const int r = tid >> 4, c4 = (tid & 15) * 4;
        for (int rr = r; rr < 64; rr += 16) {
            float4 v = *(const float4*)(memory + (size_t)(d0 + rr) * D + e0 + c4);
            T[rr][c4 + 0] = f2bf(v.x); T[rr][c4 + 1] = f2bf(v.y);
            T[rr][c4 + 2] = f2bf(v.z); T[rr][c4 + 3] = f2bf(v.w);
        }
        __syncthreads();
        for (int rr = r; rr < 64; rr += 16) {
            ushort4 o;
            o.x = T[c4 + 0][rr]; o.y = T[c4 + 1][rr];
            o.z = T[c4 + 2][rr]; o.w = T[c4 + 3][rr];
            *(ushort4*)(memT + (size_t)(e0 + rr) * D + d0 + c4) = o;
        }
    }
}

// ---------------- fused q/k/v projections: 768 blocks, XCD-colocated ----------------
// sub==2 (V) blocks write vT [b][d][s] DIRECTLY via LDS transpose (r3: kills the
// separate 1024-block transpose pass + v_b round-trip, -16MB HBM traffic).
__global__ __launch_bounds__(256) void proj_fused(const unsigned short* __restrict__ h_b,
                                                  const unsigned short* __restrict__ wq,
                                                  const unsigned short* __restrict__ wk,
                                                  const unsigned short* __restrict__ wv,
                                                  unsigned short* __restrict__ sq,
                                                  unsigned short* __restrict__ sk,
                                                  unsigned short* __restrict__ vT)
{
    __shared__ unsigned short As[2 * TSZ], Bs[2 * TSZ];
    const int id = blockIdx.x;
    const int x = id & 7, y = id >> 3;          // y: 0..95
    const int strip = x + 8 * (y % 12);         // 0..95 = sub*32 + m
    const int n     = y / 12;                   // 0..7
    const int sub = strip >> 5, m = strip & 31;
    const int m0 = m * 128, n0 = n * 128;
    const unsigned short* B = (sub == 0) ? wq : (sub == 1) ? wk : wv;

    const int tid = threadIdx.x, wave = tid >> 6, lane = tid & 63;
    const int wm = (wave >> 1) * 64, wn = (wave & 1) * 64;
    const int fr = lane & 15, g = lane >> 4;
    const int q4 = g * 4;

    floatx4 acc[4][4] = {};
    gemm_loop_db(h_b + (size_t)m0 * D, D, B + (size_t)n0 * D, D, D,
                 As, Bs, wave, lane, wm, wn, fr, g, acc);

    if (sub < 2) {
        unsigned short* C = (sub == 0) ? sq : sk;
#pragma unroll
        for (int i = 0; i < 4; ++i)
#pragma unroll
            for (int j = 0; j < 4; ++j) {
                const int col = n0 + wn + j * 16 + fr;
#pragma unroll
                for (int r = 0; r < 4; ++r) {
                    const int row = m0 + wm + i * 16 + q4 + r;
                    C[(size_t)row * D + col] = f2bf(elu1(acc[i][j][r]));
                }
            }
    } else {
        // transpose epilogue: tile rows are s (m0 = b*S + s_base), cols are d (n0).
        const int b = m0 >> 11;                  // m0 / S
        const int s_base = m0 & (S - 1);
        unsigned short (*Tr0)[72] = (unsigned short(*)[72])As;   // 64x72 = 9 KB <= 16 KB
        unsigned short (*Tr1)[72] = (unsigned short(*)[72])Bs;
        unsigned short* vb = vT + (size_t)b * D * S;
        const int r = tid >> 4, c4 = (tid & 15) * 4;
        __syncthreads();                          // all waves done reading As/Bs
#pragma unroll
        for (int sh = 0; sh < 2; ++sh) {
            // the 2 waves owning row-half sh write their 64x64 quadrants
            if ((wave >> 1) == sh) {
                unsigned short (*Tr)[72] = (wave & 1) ? Tr1 : Tr0;
#pragma unroll
                for (int i = 0; i < 4; ++i)
#pragma unroll
                    for (int j = 0; j < 4; ++j)
#pragma unroll
                        for (int rr = 0; rr < 4; ++rr)
                            Tr[i * 16 + q4 + rr][j * 16 + fr] = f2bf(acc[i][j][rr]);
            }
            __syncthreads();
            // all 256 threads write out both d-halves, coalesced 8B stores
#pragma unroll
            for (int dh = 0; dh < 2; ++dh) {
                unsigned short (*Tr)[72] = dh ? Tr1 : Tr0;
#pragma unroll
                for (int k = 0; k < 4; ++k) {
                    const int rr = r + k * 16;
                    ushort4 o;
                    o.x = Tr[c4 + 0][rr]; o.y = Tr[c4 + 1][rr];
                    o.z = Tr[c4 + 2][rr]; o.w = Tr[c4 + 3][rr];
                    *(ushort4*)(vb + (size_t)(n0 + dh * 64 + rr) * S
                                + s_base + sh * 64 + c4) = o;
                }
            }
            __syncthreads();                      // protect Tr reuse for sh=1
        }
    }
}

// ---------------- stage2: memgemm(256, swizzled) + scores(288) + rowscale(1024)
__global__ __launch_bounds__(256) void stage2(const unsigned short* __restrict__ sq,
                                              const unsigned short* __restrict__ sk,
                                              const unsigned short* __restrict__ memT,
                                              const float* __restrict__ mnorm,
                                              const float* __restrict__ gate,
                                              unsigned short* __restrict__ combm,
                                              unsigned short* __restrict__ Sbuf2,
                                              float* __restrict__ rowscale)
{
    __shared__ unsigned short As[2 * TSZ], Bs[2 * TSZ];
    const int id = blockIdx.x, tid = threadIdx.x;
    const int wave = tid >> 6, lane = tid & 63;
    const int wm = (wave >> 1) * 64, wn = (wave & 1) * 64;
    const int fr = lane & 15, g = lane >> 4;
    const int q4 = g * 4;

    if (id < 256) {
        // combm = f2bf(sq @ memT^T); XCD swizzle: 8 n-tiles of one m-strip colocated
        const int x = id & 7, y = id >> 3;      // y: 0..31
        const int m0 = (x + 8 * (y & 3)) * 128; // strip 0..31
        const int n0 = (y >> 2) * 128;          // 0..7
        floatx4 acc[4][4] = {};
        gemm_loop_db(sq + (size_t)m0 * D, D, memT + (size_t)n0 * D, D, D,
                     As, Bs, wave, lane, wm, wn, fr, g, acc);
#pragma unroll
        for (int i = 0; i < 4; ++i)
#pragma unroll
            for (int j = 0; j < 4; ++j) {
                const int col = n0 + wn + j * 16 + fr;
#pragma unroll
                for (int r = 0; r < 4; ++r)
                    combm[(size_t)(m0 + wm + i * 16 + q4 + r) * D + col] = f2bf(acc[i][j][r]);
            }
    } else if (id < 544) {
        // scores pair (c,j): rows of chunk c, col slab j*CH
        const int t = id - 256;
        const int b = t / 144, rem = t % 144;
        const int p = rem >> 2, tt = rem & 3;
        const int it = tt >> 1, jt = tt & 1;
        int c = 0;
        while ((c + 1) * (c + 2) / 2 <= p) ++c;
        const int j = p - c * (c + 1) / 2;
        unsigned short* Srow0 = Sbuf2 + (size_t)(b * NCH + c) * CH * S;

        if (j == c && jt > it) {  // fully above diagonal: zero-fill
            const int row = it * 128 + (tid >> 1);
            unsigned short* zp = Srow0 + (size_t)row * S + j * CH + jt * 128 + (tid & 1) * 64;
            uint4 z4 = make_uint4(0, 0, 0, 0);
#pragma unroll
            for (int i = 0; i < 8; ++i) *(uint4*)(zp + i * 8) = z4;
            return;
        }
        floatx4 acc[4][4] = {};
        gemm_loop_db(sq + ((size_t)b * S + (size_t)c * CH + it * 128) * D, D,
                     sk + ((size_t)b * S + (size_t)j * CH + jt * 128) * D, D, D,
                     As, Bs, wave, lane, wm, wn, fr, g, acc);
        const bool diag = (j == c && it == jt);
#pragma unroll
        for (int i = 0; i < 4; ++i)
#pragma unroll
            for (int jj = 0; jj < 4; ++jj) {
                const int col = jt * 128 + wn + jj * 16 + fr;   // within slab
#pragma unroll
                for (int r = 0; r < 4; ++r) {
                    const int row = it * 128 + wm + i * 16 + q4 + r;
                    float val = acc[i][jj][r];
                    if (diag && col > row) val = 0.f;
                    Srow0[(size_t)row * S + j * CH + col] = f2bf(val);
                }
            }
    } else {
        // rowscale[row] = g*active / clip(sq_row . mnorm)  — vectorized short8/float4
        const int row = (id - 544) * 4 + wave;
        const unsigned short* sr = sq + (size_t)row * D;
        float dot = 0.f, msum = 0.f;
#pragma unroll
        for (int p = 0; p < 2; ++p) {
            const int d0 = p * 512 + lane * 8;
            short8 sv = *(const short8*)(sr + d0);
            float4 m0 = *(const float4*)(mnorm + d0);
            float4 m1 = *(const float4*)(mnorm + d0 + 4);
            dot += bf2f((unsigned short)sv[0]) * m0.x + bf2f((unsigned short)sv[1]) * m0.y
                 + bf2f((unsigned short)sv[2]) * m0.z + bf2f((unsigned short)sv[3]) * m0.w
                 + bf2f((unsigned short)sv[4]) * m1.x + bf2f((unsigned short)sv[5]) * m1.y
                 + bf2f((unsigned short)sv[6]) * m1.z + bf2f((unsigned short)sv[7]) * m1.w;
            msum += m0.x + m0.y + m0.z + m0.w + m1.x + m1.y + m1.z + m1.w;
        }
        dot = wave_reduce(dot);
        msum = wave_reduce(msum);
        if (lane == 0) {
            const float gg = sigmoidf_(gate[0]);
            const float active = (msum >= EPSF) ? 1.f : 0.f;
            rowscale[row] = gg * active / fmaxf(dot, EPSF);
        }
    }
}

// ---------------- pv: combm = f2bf(combm*rowscale + (1-g)*(S@v)/den), den in-register ----------
__global__ __launch_bounds__(256) void pv64(const unsigned short* __restrict__ Sbuf2,
                                            const unsigned short* __restrict__ vT,
                                            const float* __restrict__ rowscale,
                                            const float* __restrict__ gate,
                                            unsigned short* __restrict__ combm)
{
    __shared__ unsigned short As2[2 * TA64], Bs2[2 * TSZ];
    const int id = blockIdx.x, tid = threadIdx.x;
    const int wave = tid >> 6, lane = tid & 63;
    const int wm = (wave >> 1) * 32, wn = (wave & 1) * 64;
    const int fr = lane & 15, g = lane >> 4;
    const int q4 = g * 4;

    const int x = id & 7, y = id >> 3;          // y: 0..63
    const int g_ = x + 8 * (y & 7);             // group 0..63 = (b, c-rev, i)
    const int e  = y >> 3;                      // 0..7
    const int b = g_ >> 5;
    const int rem = g_ & 31;
    const int c = (NCH - 1) - (rem >> 2);       // long-K groups first within XCD
    const int i0 = (rem & 3) * 64, e0 = e * 128;

    const short one_bf = (short)0x3F80;
    short8 bones = {one_bf, one_bf, one_bf, one_bf, one_bf, one_bf, one_bf, one_bf};

    floatx4 acc[2][4] = {};
    floatx4 accd[2] = {};
    gemm_loop_db64d(Sbuf2 + ((size_t)(b * NCH + c) * CH + i0) * S, S,
                    vT + (size_t)b * D * S + (size_t)e0 * S, S, (c + 1) * CH,
                    As2, Bs2, wave, lane, wm, wn, fr, g, acc, accd, bones);

    const float gg = sigmoidf_(gate[0]);
    const float wloc = 1.f - gg;
#pragma unroll
    for (int i = 0; i < 2; ++i)
#pragma unroll
        for (int j = 0; j < 4; ++j) {
            const int col = e0 + wn + j * 16 + fr;
#pragma unroll
            for (int r = 0; r < 4; ++r) {
                const int li = i0 + wm + i * 16 + q4 + r;
                const int rg = b * S + c * CH + li;
                const float inv = wloc / fmaxf(accd[i][r], EPSF);
                const size_t idx = (size_t)rg * D + col;
                combm[idx] = f2bf(bf2f(combm[idx]) * rowscale[rg] + acc[i][j][r] * inv);
            }
        }
}

// ---------------- out-proj: out = combm @ wo^T (fp32), 512 blocks, XCD-colocated --------------
__global__ __launch_bounds__(256) void outproj64(const unsigned short* __restrict__ A,
                                                 const unsigned short* __restrict__ wo,
                                                 float* __restrict__ out)
{
    __shared__ unsigned short As2[2 * TA64], Bs2[2 * TSZ];
    const int id = blockIdx.x, tid = threadIdx.x;
    const int wave = tid >> 6, lane = tid & 63;
    const int wm = (wave >> 1) * 32, wn = (wave & 1) * 64;
    const int fr = lane & 15, g = lane >> 4;
    const int q4 = g * 4;

    const int x = id & 7, y = id >> 3;          // y: 0..63
    const int m0 = (x + 8 * (y & 7)) * 64;      // strip 0..63 (64-row tiles)
    const int n0 = (y >> 3) * 128;              // 0..7

    floatx4 acc[2][4] = {};
    gemm_loop_db64(A + (size_t)m0 * D, D, wo + (size_t)n0 * D, D, D,
                   As2, Bs2, wave, lane, wm, wn, fr, g, acc);

#pragma unroll
    for (int i = 0; i < 2; ++i)
#pragma unroll
        for (int j = 0; j < 4; ++j) {
            const int col = n0 + wn + j * 16 + fr;
#pragma unroll
            for (int r = 0; r < 4; ++r)
                out[(size_t)(m0 + wm + i * 16 + q4 + r) * D + col] = acc[i][j][r];
        }
}

extern "C" void kernel_launch(void* const* d_in, const int* in_sizes, int n_in,
                              void* d_out, int out_size, void* d_ws, size_t ws_size,
                              hipStream_t stream)
{
    const float* h      = (const float*)d_in[0];
    const float* w_q    = (const float*)d_in[1];
    const float* w_k    = (const float*)d_in[2];
    const float* w_v    = (const float*)d_in[3];
    const float* w_o    = (const float*)d_in[4];
    const float* gate   = (const float*)d_in[5];
    const float* memory = (const float*)d_in[6];
    const float* mnorm  = (const float*)d_in[7];
    float* out = (float*)d_out;

    // ---- workspace (~67 MB), no aliasing; v_b removed (r3) ----
    unsigned short* h_b   = (unsigned short*)d_ws;               // M*D (8 MB)
    unsigned short* wq_b  = h_b + (size_t)M * D;                 // D*D
    unsigned short* wk_b  = wq_b + (size_t)D * D;                // D*D
    unsigned short* wv_b  = wk_b + (size_t)D * D;                // D*D
    unsigned short* wo_b  = wv_b + (size_t)D * D;                // D*D
    unsigned short* memT  = wo_b + (size_t)D * D;                // D*D (2 MB)
    unsigned short* sq_b  = memT + (size_t)D * D;                // M*D (8 MB)
    unsigned short* sk_b  = sq_b + (size_t)M * D;                // M*D (8 MB)
    unsigned short* vT    = sk_b + (size_t)M * D;                // M*D (8 MB)
    unsigned short* Sbuf2 = vT + (size_t)M * D;                  // Bv*NCH*CH*S (16.8 MB)
    unsigned short* combm = Sbuf2 + (size_t)Bv * NCH * CH * S;   // M*D (8 MB)
    float* rowscale = (float*)(combm + (size_t)M * D);           // M fp32

    dim3 blk(256);

    prep<<<8448, blk, 0, stream>>>(h, w_q, w_k, w_v, w_o, memory,
                                   h_b, wq_b, wk_b, wv_b, wo_b, memT);
    proj_fused<<<768, blk, 0, stream>>>(h_b, wq_b, wk_b, wv_b, sq_b, sk_b, vT);
    stage2<<<1568, blk, 0, stream>>>(sq_b, sk_b, memT, mnorm, gate,
                                     combm, Sbuf2, rowscale);
    pv64<<<512, blk, 0, stream>>>(Sbuf2, vT, rowscale, gate, combm);
    outproj64<<<512, blk, 0, stream>>>(combm, wo_b, out);
}

// Round 4
// 233.464 us; speedup vs baseline: 1.0620x; 1.0620x over previous
//
#include <hip/hip_runtime.h>
#include <cstddef>

#define EPSF 1e-6f

constexpr int D   = 1024;
constexpr int Bv  = 2;
constexpr int S   = 2048;
constexpr int M   = Bv * S;    // 4096
constexpr int CH  = 256;       // chunk
constexpr int NCH = S / CH;    // 8

constexpr int TSZ  = 128 * 32; // 128-row LDS tile (elems, 8 KB)
constexpr int TA64 = 64 * 32;  // 64-row LDS tile (elems, 4 KB)

typedef __attribute__((ext_vector_type(8))) short short8;   // 8 bf16
typedef __attribute__((ext_vector_type(4))) float floatx4;  // 4 fp32

__device__ __forceinline__ float elu1(float x) { return x > 0.f ? x + 1.f : __expf(x); }
__device__ __forceinline__ float sigmoidf_(float x) { return 1.f / (1.f + __expf(-x)); }
__device__ __forceinline__ unsigned short f2bf(float x) {
    unsigned u = __float_as_uint(x);
    return (unsigned short)((u + 0x7fffu + ((u >> 16) & 1u)) >> 16);
}
__device__ __forceinline__ float bf2f(unsigned short h) {
    return __uint_as_float(((unsigned)h) << 16);
}
__device__ __forceinline__ float wave_reduce(float x) {
#pragma unroll
    for (int off = 32; off > 0; off >>= 1) x += __shfl_down(x, off);
    return x;
}

// async global->LDS, 16B per lane (dest = wave-uniform base + lane*16)
__device__ __forceinline__ void gl_lds16(const unsigned short* g, unsigned short* l) {
    __builtin_amdgcn_global_load_lds(
        (const __attribute__((address_space(1))) void*)g,
        (__attribute__((address_space(3))) void*)l, 16, 0, 0);
}

// ---- XOR-swizzled LDS tiles (both-sides, LDS dest linear; r2: conflicts->0) ----
// Tile [R][32] bf16 (64B rows): physical 16B-chunk p of row r holds logical
// chunk c = p ^ ((r>>1)&3). Reads apply the same XOR.
// r4: staging addresses are INDUCTION VARIABLES — per-lane global pointers are
// computed once per gemm call and advanced += 32/step (kills the per-step
// 64-bit mul chains that made VALUBusy ~47%).

// 16 MFMAs, 128x128 tile, wave quadrant (wm,wn in {0,64}); LDS base hoisted,
// row offsets fold into ds_read immediate offsets (i*512 elems = 1024B).
__device__ __forceinline__ void mfma_step(const unsigned short* As, const unsigned short* Bs,
                                          int wm, int wn, int fr, int g, floatx4 acc[4][4]) {
    const int off = ((g ^ ((fr >> 1) & 3)) << 3);
    const unsigned short* Ar = As + (wm + fr) * 32 + off;
    const unsigned short* Br = Bs + (wn + fr) * 32 + off;
    short8 af[4], bf[4];
#pragma unroll
    for (int i = 0; i < 4; ++i) af[i] = *(const short8*)&Ar[i * 512];
#pragma unroll
    for (int j = 0; j < 4; ++j) bf[j] = *(const short8*)&Br[j * 512];
#pragma unroll
    for (int i = 0; i < 4; ++i)
#pragma unroll
        for (int j = 0; j < 4; ++j)
            acc[i][j] = __builtin_amdgcn_mfma_f32_16x16x32_bf16(af[i], bf[j], acc[i][j], 0, 0, 0);
}

// 8 MFMAs + 2 ones-MFMAs (rowsum), 64x128 tile (wm in {0,32}, wn in {0,64})
__device__ __forceinline__ void mfma_step64d(const unsigned short* As, const unsigned short* Bs,
                                             int wm, int wn, int fr, int g,
                                             floatx4 acc[2][4], floatx4 accd[2], short8 bones) {
    const int off = ((g ^ ((fr >> 1) & 3)) << 3);
    const unsigned short* Ar = As + (wm + fr) * 32 + off;
    const unsigned short* Br = Bs + (wn + fr) * 32 + off;
    short8 af[2], bf[4];
#pragma unroll
    for (int i = 0; i < 2; ++i) af[i] = *(const short8*)&Ar[i * 512];
#pragma unroll
    for (int j = 0; j < 4; ++j) bf[j] = *(const short8*)&Br[j * 512];
#pragma unroll
    for (int i = 0; i < 2; ++i) {
#pragma unroll
        for (int j = 0; j < 4; ++j)
            acc[i][j] = __builtin_amdgcn_mfma_f32_16x16x32_bf16(af[i], bf[j], acc[i][j], 0, 0, 0);
        accd[i] = __builtin_amdgcn_mfma_f32_16x16x32_bf16(af[i], bones, accd[i], 0, 0, 0);
    }
}

// 8 MFMAs, 64x128 tile (no rowsum)
__device__ __forceinline__ void mfma_step64(const unsigned short* As, const unsigned short* Bs,
                                            int wm, int wn, int fr, int g, floatx4 acc[2][4]) {
    const int off = ((g ^ ((fr >> 1) & 3)) << 3);
    const unsigned short* Ar = As + (wm + fr) * 32 + off;
    const unsigned short* Br = Bs + (wn + fr) * 32 + off;
    short8 af[2], bf[4];
#pragma unroll
    for (int i = 0; i < 2; ++i) af[i] = *(const short8*)&Ar[i * 512];
#pragma unroll
    for (int j = 0; j < 4; ++j) bf[j] = *(const short8*)&Br[j * 512];
#pragma unroll
    for (int i = 0; i < 2; ++i)
#pragma unroll
        for (int j = 0; j < 4; ++j)
            acc[i][j] = __builtin_amdgcn_mfma_f32_16x16x32_bf16(af[i], bf[j], acc[i][j], 0, 0, 0);
}

// Double-buffered K-loop, 128x128 tile; pointer-increment staging.
__device__ __forceinline__ void gemm_loop_db(const unsigned short* Ag, int sA,
                                             const unsigned short* Bg, int sB, int Kk,
                                             unsigned short* As, unsigned short* Bs,
                                             int wave, int lane, int wm, int wn, int fr, int g,
                                             floatx4 acc[4][4]) {
    const int t   = (wave << 6) + lane;
    const int row = t >> 2;
    const int cb  = (((t & 3) ^ ((row >> 1) & 3)) << 3);   // pre-swizzled source chunk
    const unsigned short* pa0 = Ag + (size_t)row * sA + cb;
    const unsigned short* pa1 = Ag + (size_t)(row + 64) * sA + cb;
    const unsigned short* pb0 = Bg + (size_t)row * sB + cb;
    const unsigned short* pb1 = Bg + (size_t)(row + 64) * sB + cb;
    unsigned short* dA = As + (wave << 9);
    unsigned short* dB = Bs + (wave << 9);
    __syncthreads();
    gl_lds16(pa0, dA); gl_lds16(pa1, dA + 2048);
    gl_lds16(pb0, dB); gl_lds16(pb1, dB + 2048);
    int buf = 0;
    for (int k0 = 32; k0 < Kk; k0 += 32) {
        pa0 += 32; pa1 += 32; pb0 += 32; pb1 += 32;
        __syncthreads();
        const int nb = buf ^ 1;
        unsigned short* dA2 = dA + nb * TSZ;
        unsigned short* dB2 = dB + nb * TSZ;
        gl_lds16(pa0, dA2); gl_lds16(pa1, dA2 + 2048);
        gl_lds16(pb0, dB2); gl_lds16(pb1, dB2 + 2048);
        mfma_step(As + buf * TSZ, Bs + buf * TSZ, wm, wn, fr, g, acc);
        buf = nb;
    }
    __syncthreads();
    mfma_step(As + buf * TSZ, Bs + buf * TSZ, wm, wn, fr, g, acc);
}

// Double-buffered K-loop, 64x128 tile, with in-register rowsum (den)
__device__ __forceinline__ void gemm_loop_db64d(const unsigned short* Ag, int sA,
                                                const unsigned short* Bg, int sB, int Kk,
                                                unsigned short* As, unsigned short* Bs,
                                                int wave, int lane, int wm, int wn, int fr, int g,
                                                floatx4 acc[2][4], floatx4 accd[2], short8 bones) {
    const int t   = (wave << 6) + lane;
    const int row = t >> 2;
    const int cb  = (((t & 3) ^ ((row >> 1) & 3)) << 3);
    const unsigned short* pa0 = Ag + (size_t)row * sA + cb;
    const unsigned short* pb0 = Bg + (size_t)row * sB + cb;
    const unsigned short* pb1 = Bg + (size_t)(row + 64) * sB + cb;
    unsigned short* dA = As + (wave << 9);
    unsigned short* dB = Bs + (wave << 9);
    __syncthreads();
    gl_lds16(pa0, dA);
    gl_lds16(pb0, dB); gl_lds16(pb1, dB + 2048);
    int buf = 0;
    for (int k0 = 32; k0 < Kk; k0 += 32) {
        pa0 += 32; pb0 += 32; pb1 += 32;
        __syncthreads();
        const int nb = buf ^ 1;
        unsigned short* dA2 = dA + nb * TA64;
        unsigned short* dB2 = dB + nb * TSZ;
        gl_lds16(pa0, dA2);
        gl_lds16(pb0, dB2); gl_lds16(pb1, dB2 + 2048);
        mfma_step64d(As + buf * TA64, Bs + buf * TSZ, wm, wn, fr, g, acc, accd, bones);
        buf = nb;
    }
    __syncthreads();
    mfma_step64d(As + buf * TA64, Bs + buf * TSZ, wm, wn, fr, g, acc, accd, bones);
}

// Double-buffered K-loop, 64x128 tile (plain)
__device__ __forceinline__ void gemm_loop_db64(const unsigned short* Ag, int sA,
                                               const unsigned short* Bg, int sB, int Kk,
                                               unsigned short* As, unsigned short* Bs,
                                               int wave, int lane, int wm, int wn, int fr, int g,
                                               floatx4 acc[2][4]) {
    const int t   = (wave << 6) + lane;
    const int row = t >> 2;
    const int cb  = (((t & 3) ^ ((row >> 1) & 3)) << 3);
    const unsigned short* pa0 = Ag + (size_t)row * sA + cb;
    const unsigned short* pb0 = Bg + (size_t)row * sB + cb;
    const unsigned short* pb1 = Bg + (size_t)(row + 64) * sB + cb;
    unsigned short* dA = As + (wave << 9);
    unsigned short* dB = Bs + (wave << 9);
    __syncthreads();
    gl_lds16(pa0, dA);
    gl_lds16(pb0, dB); gl_lds16(pb1, dB + 2048);
    int buf = 0;
    for (int k0 = 32; k0 < Kk; k0 += 32) {
        pa0 += 32; pb0 += 32; pb1 += 32;
        __syncthreads();
        const int nb = buf ^ 1;
        unsigned short* dA2 = dA + nb * TA64;
        unsigned short* dB2 = dB + nb * TSZ;
        gl_lds16(pa0, dA2);
        gl_lds16(pb0, dB2); gl_lds16(pb1, dB2 + 2048);
        mfma_step64(As + buf * TA64, Bs + buf * TSZ, wm, wn, fr, g, acc);
        buf = nb;
    }
    __syncthreads();
    mfma_step64(As + buf * TA64, Bs + buf * TSZ, wm, wn, fr, g, acc);
}

// ---------------- prep: cvt h + cvt 4 weights + transpose memory ----------------
__global__ __launch_bounds__(256) void prep(const float* __restrict__ h,
                                            const float* __restrict__ w_q, const float* __restrict__ w_k,
                                            const float* __restrict__ w_v, const float* __restrict__ w_o,
                                            const float* __restrict__ memory,
                                            unsigned short* __restrict__ h_b,
                                            unsigned short* __restrict__ wq_b, unsigned short* __restrict__ wk_b,
                                            unsigned short* __restrict__ wv_b, unsigned short* __restrict__ wo_b,
                                            unsigned short* __restrict__ memT)
{
    __shared__ unsigned short T[64][72];
    const int id = blockIdx.x, tid = threadIdx.x;
    if (id < 4096) {
        const size_t i = ((size_t)id * 256 + tid) * 4;
        float4 v = *(const float4*)(h + i);
        ushort4 o; o.x = f2bf(v.x); o.y = f2bf(v.y); o.z = f2bf(v.z); o.w = f2bf(v.w);
        *(ushort4*)(h_b + i) = o;
    } else if (id < 8192) {
        const int t = id - 4096, which = t >> 10;
        const float* in = (which == 0) ? w_q : (which == 1) ? w_k : (which == 2) ? w_v : w_o;
        unsigned short* out = (which == 0) ? wq_b : (which == 1) ? wk_b : (which == 2) ? wv_b : wo_b;
        const size_t i = ((size_t)(t & 1023) * 256 + tid) * 4;
        float4 v = *(const float4*)(in + i);
        ushort4 o; o.x = f2bf(v.x); o.y = f2bf(v.y); o.z = f2bf(v.z); o.w = f2bf(v.w);
        *(ushort4*)(out + i) = o;
    } else {
        const int t = id - 8192;
        const int d0 = (t >> 4) * 64, e0 = (t & 15) * 64;
        const int r = tid >> 4, c4 = (tid & 15) * 4;
        for (int rr = r; rr < 64; rr += 16) {
            float4 v = *(const float4*)(memory + (size_t)(d0 + rr) * D + e0 + c4);
            T[rr][c4 + 0] = f2bf(v.x); T[rr][c4 + 1] = f2bf(v.y);
            T[rr][c4 + 2] = f2bf(v.z); T[rr][c4 + 3] = f2bf(v.w);
        }
        __syncthreads();
        for (int rr = r; rr < 64; rr += 16) {
            ushort4 o;
            o.x = T[c4 + 0][rr]; o.y = T[c4 + 1][rr];
            o.z = T[c4 + 2][rr]; o.w = T[c4 + 3][rr];
            *(ushort4*)(memT + (size_t)(e0 + rr) * D + d0 + c4) = o;
        }
    }
}

// ---------------- fused q/k/v projections: 768 blocks, XCD-colocated ----------------
__global__ __launch_bounds__(256) void proj_fused(const unsigned short* __restrict__ h_b,
                                                  const unsigned short* __restrict__ wq,
                                                  const unsigned short* __restrict__ wk,
                                                  const unsigned short* __restrict__ wv,
                                                  unsigned short* __restrict__ sq,
                                                  unsigned short* __restrict__ sk,
                                                  unsigned short* __restrict__ v)
{
    __shared__ unsigned short As[2 * TSZ], Bs[2 * TSZ];
    const int id = blockIdx.x;
    const int x = id & 7, y = id >> 3;          // y: 0..95
    const int strip = x + 8 * (y % 12);         // 0..95 = sub*32 + m
    const int n     = y / 12;                   // 0..7
    const int sub = strip >> 5, m = strip & 31;
    const int m0 = m * 128, n0 = n * 128;
    const unsigned short* B = (sub == 0) ? wq : (sub == 1) ? wk : wv;
    unsigned short* C = (sub == 0) ? sq : (sub == 1) ? sk : v;

    const int tid = threadIdx.x, wave = tid >> 6, lane = tid & 63;
    const int wm = (wave >> 1) * 64, wn = (wave & 1) * 64;
    const int fr = lane & 15, g = lane >> 4;
    const int q4 = g * 4;

    floatx4 acc[4][4] = {};
    gemm_loop_db(h_b + (size_t)m0 * D, D, B + (size_t)n0 * D, D, D,
                 As, Bs, wave, lane, wm, wn, fr, g, acc);

#pragma unroll
    for (int i = 0; i < 4; ++i)
#pragma unroll
        for (int j = 0; j < 4; ++j) {
            const int col = n0 + wn + j * 16 + fr;
#pragma unroll
            for (int r = 0; r < 4; ++r) {
                const int row = m0 + wm + i * 16 + q4 + r;
                float val = acc[i][j][r];
                if (sub < 2) val = elu1(val);
                C[(size_t)row * D + col] = f2bf(val);
            }
        }
}

// ---------------- stage2: memgemm(256, swizzled) + scores(288) + v-transpose(1024) + rowscale(1024)
__global__ __launch_bounds__(256) void stage2(const unsigned short* __restrict__ sq,
                                              const unsigned short* __restrict__ sk,
                                              const unsigned short* __restrict__ memT,
                                              const unsigned short* __restrict__ v_b,
                                              const float* __restrict__ mnorm,
                                              const float* __restrict__ gate,
                                              unsigned short* __restrict__ combm,
                                              unsigned short* __restrict__ Sbuf2,
                                              unsigned short* __restrict__ vT,
                                              float* __restrict__ rowscale)
{
    __shared__ unsigned short As[2 * TSZ], Bs[2 * TSZ];
    const int id = blockIdx.x, tid = threadIdx.x;
    const int wave = tid >> 6, lane = tid & 63;
    const int wm = (wave >> 1) * 64, wn = (wave & 1) * 64;
    const int fr = lane & 15, g = lane >> 4;
    const int q4 = g * 4;

    if (id < 256) {
        // combm = f2bf(sq @ memT^T); XCD swizzle: 8 n-tiles of one m-strip colocated
        const int x = id & 7, y = id >> 3;      // y: 0..31
        const int m0 = (x + 8 * (y & 3)) * 128; // strip 0..31
        const int n0 = (y >> 2) * 128;          // 0..7
        floatx4 acc[4][4] = {};
        gemm_loop_db(sq + (size_t)m0 * D, D, memT + (size_t)n0 * D, D, D,
                     As, Bs, wave, lane, wm, wn, fr, g, acc);
#pragma unroll
        for (int i = 0; i < 4; ++i)
#pragma unroll
            for (int j = 0; j < 4; ++j) {
                const int col = n0 + wn + j * 16 + fr;
#pragma unroll
                for (int r = 0; r < 4; ++r)
                    combm[(size_t)(m0 + wm + i * 16 + q4 + r) * D + col] = f2bf(acc[i][j][r]);
            }
    } else if (id < 544) {
        // scores pair (c,j): rows of chunk c, col slab j*CH
        const int t = id - 256;
        const int b = t / 144, rem = t % 144;
        const int p = rem >> 2, tt = rem & 3;
        const int it = tt >> 1, jt = tt & 1;
        int c = 0;
        while ((c + 1) * (c + 2) / 2 <= p) ++c;
        const int j = p - c * (c + 1) / 2;
        unsigned short* Srow0 = Sbuf2 + (size_t)(b * NCH + c) * CH * S;

        if (j == c && jt > it) {  // fully above diagonal: zero-fill
            const int row = it * 128 + (tid >> 1);
            unsigned short* zp = Srow0 + (size_t)row * S + j * CH + jt * 128 + (tid & 1) * 64;
            uint4 z4 = make_uint4(0, 0, 0, 0);
#pragma unroll
            for (int i = 0; i < 8; ++i) *(uint4*)(zp + i * 8) = z4;
            return;
        }
        floatx4 acc[4][4] = {};
        gemm_loop_db(sq + ((size_t)b * S + (size_t)c * CH + it * 128) * D, D,
                     sk + ((size_t)b * S + (size_t)j * CH + jt * 128) * D, D, D,
                     As, Bs, wave, lane, wm, wn, fr, g, acc);
        const bool diag = (j == c && it == jt);
#pragma unroll
        for (int i = 0; i < 4; ++i)
#pragma unroll
            for (int jj = 0; jj < 4; ++jj) {
                const int col = jt * 128 + wn + jj * 16 + fr;   // within slab
#pragma unroll
                for (int r = 0; r < 4; ++r) {
                    const int row = it * 128 + wm + i * 16 + q4 + r;
                    float val = acc[i][jj][r];
                    if (diag && col > row) val = 0.f;
                    Srow0[(size_t)row * S + j * CH + col] = f2bf(val);
                }
            }
    } else if (id < 1568) {
        // transpose v_b [b][s][d] -> vT [b][d][s], 64x64 tiles
        unsigned short (*T)[72] = (unsigned short(*)[72])As;
        const int t = id - 544;
        const int b = t >> 9, rem = t & 511;
        const int s0 = (rem >> 4) * 64, d0 = (rem & 15) * 64;
        const int r = tid >> 4, c4 = (tid & 15) * 4;
        const unsigned short* ip = v_b + (size_t)b * S * D;
        for (int rr = r; rr < 64; rr += 16) {
            ushort4 vv = *(const ushort4*)(ip + (size_t)(s0 + rr) * D + d0 + c4);
            T[rr][c4 + 0] = vv.x; T[rr][c4 + 1] = vv.y; T[rr][c4 + 2] = vv.z; T[rr][c4 + 3] = vv.w;
        }
        __syncthreads();
        unsigned short* op = vT + (size_t)b * D * S;
        for (int rr = r; rr < 64; rr += 16) {
            ushort4 o;
            o.x = T[c4 + 0][rr]; o.y = T[c4 + 1][rr];
            o.z = T[c4 + 2][rr]; o.w = T[c4 + 3][rr];
            *(ushort4*)(op + (size_t)(d0 + rr) * S + s0 + c4) = o;
        }
    } else {
        // rowscale[row] = g*active / clip(sq_row . mnorm) — vectorized short8/float4
        const int row = (id - 1568) * 4 + wave;
        const unsigned short* sr = sq + (size_t)row * D;
        float dot = 0.f, msum = 0.f;
#pragma unroll
        for (int p = 0; p < 2; ++p) {
            const int d0 = p * 512 + lane * 8;
            short8 sv = *(const short8*)(sr + d0);
            float4 m0 = *(const float4*)(mnorm + d0);
            float4 m1 = *(const float4*)(mnorm + d0 + 4);
            dot += bf2f((unsigned short)sv[0]) * m0.x + bf2f((unsigned short)sv[1]) * m0.y
                 + bf2f((unsigned short)sv[2]) * m0.z + bf2f((unsigned short)sv[3]) * m0.w
                 + bf2f((unsigned short)sv[4]) * m1.x + bf2f((unsigned short)sv[5]) * m1.y
                 + bf2f((unsigned short)sv[6]) * m1.z + bf2f((unsigned short)sv[7]) * m1.w;
            msum += m0.x + m0.y + m0.z + m0.w + m1.x + m1.y + m1.z + m1.w;
        }
        dot = wave_reduce(dot);
        msum = wave_reduce(msum);
        if (lane == 0) {
            const float gg = sigmoidf_(gate[0]);
            const float active = (msum >= EPSF) ? 1.f : 0.f;
            rowscale[row] = gg * active / fmaxf(dot, EPSF);
        }
    }
}

// ---------------- pv: combm = f2bf(combm*rowscale + (1-g)*(S@v)/den), den in-register ----------
__global__ __launch_bounds__(256) void pv64(const unsigned short* __restrict__ Sbuf2,
                                            const unsigned short* __restrict__ vT,
                                            const float* __restrict__ rowscale,
                                            const float* __restrict__ gate,
                                            unsigned short* __restrict__ combm)
{
    __shared__ unsigned short As2[2 * TA64], Bs2[2 * TSZ];
    const int id = blockIdx.x, tid = threadIdx.x;
    const int wave = tid >> 6, lane = tid & 63;
    const int wm = (wave >> 1) * 32, wn = (wave & 1) * 64;
    const int fr = lane & 15, g = lane >> 4;
    const int q4 = g * 4;

    const int x = id & 7, y = id >> 3;          // y: 0..63
    const int g_ = x + 8 * (y & 7);             // group 0..63 = (b, c-rev, i)
    const int e  = y >> 3;                      // 0..7
    const int b = g_ >> 5;
    const int rem = g_ & 31;
    const int c = (NCH - 1) - (rem >> 2);       // long-K groups first within XCD
    const int i0 = (rem & 3) * 64, e0 = e * 128;

    const short one_bf = (short)0x3F80;
    short8 bones = {one_bf, one_bf, one_bf, one_bf, one_bf, one_bf, one_bf, one_bf};

    floatx4 acc[2][4] = {};
    floatx4 accd[2] = {};
    gemm_loop_db64d(Sbuf2 + ((size_t)(b * NCH + c) * CH + i0) * S, S,
                    vT + (size_t)b * D * S + (size_t)e0 * S, S, (c + 1) * CH,
                    As2, Bs2, wave, lane, wm, wn, fr, g, acc, accd, bones);

    const float gg = sigmoidf_(gate[0]);
    const float wloc = 1.f - gg;
#pragma unroll
    for (int i = 0; i < 2; ++i)
#pragma unroll
        for (int j = 0; j < 4; ++j) {
            const int col = e0 + wn + j * 16 + fr;
#pragma unroll
            for (int r = 0; r < 4; ++r) {
                const int li = i0 + wm + i * 16 + q4 + r;
                const int rg = b * S + c * CH + li;
                const float inv = wloc / fmaxf(accd[i][r], EPSF);
                const size_t idx = (size_t)rg * D + col;
                combm[idx] = f2bf(bf2f(combm[idx]) * rowscale[rg] + acc[i][j][r] * inv);
            }
        }
}

// ---------------- out-proj: out = combm @ wo^T (fp32), 512 blocks, XCD-colocated --------------
__global__ __launch_bounds__(256) void outproj64(const unsigned short* __restrict__ A,
                                                 const unsigned short* __restrict__ wo,
                                                 float* __restrict__ out)
{
    __shared__ unsigned short As2[2 * TA64], Bs2[2 * TSZ];
    const int id = blockIdx.x, tid = threadIdx.x;
    const int wave = tid >> 6, lane = tid & 63;
    const int wm = (wave >> 1) * 32, wn = (wave & 1) * 64;
    const int fr = lane & 15, g = lane >> 4;
    const int q4 = g * 4;

    const int x = id & 7, y = id >> 3;          // y: 0..63
    const int m0 = (x + 8 * (y & 7)) * 64;      // strip 0..63 (64-row tiles)
    const int n0 = (y >> 3) * 128;              // 0..7

    floatx4 acc[2][4] = {};
    gemm_loop_db64(A + (size_t)m0 * D, D, wo + (size_t)n0 * D, D, D,
                   As2, Bs2, wave, lane, wm, wn, fr, g, acc);

#pragma unroll
    for (int i = 0; i < 2; ++i)
#pragma unroll
        for (int j = 0; j < 4; ++j) {
            const int col = n0 + wn + j * 16 + fr;
#pragma unroll
            for (int r = 0; r < 4; ++r)
                out[(size_t)(m0 + wm + i * 16 + q4 + r) * D + col] = acc[i][j][r];
        }
}

extern "C" void kernel_launch(void* const* d_in, const int* in_sizes, int n_in,
                              void* d_out, int out_size, void* d_ws, size_t ws_size,
                              hipStream_t stream)
{
    const float* h      = (const float*)d_in[0];
    const float* w_q    = (const float*)d_in[1];
    const float* w_k    = (const float*)d_in[2];
    const float* w_v    = (const float*)d_in[3];
    const float* w_o    = (const float*)d_in[4];
    const float* gate   = (const float*)d_in[5];
    const float* memory = (const float*)d_in[6];
    const float* mnorm  = (const float*)d_in[7];
    float* out = (float*)d_out;

    // ---- workspace (~75 MB), no aliasing ----
    unsigned short* h_b   = (unsigned short*)d_ws;               // M*D (8 MB)
    unsigned short* wq_b  = h_b + (size_t)M * D;                 // D*D
    unsigned short* wk_b  = wq_b + (size_t)D * D;                // D*D
    unsigned short* wv_b  = wk_b + (size_t)D * D;                // D*D
    unsigned short* wo_b  = wv_b + (size_t)D * D;                // D*D
    unsigned short* memT  = wo_b + (size_t)D * D;                // D*D (2 MB)
    unsigned short* sq_b  = memT + (size_t)D * D;                // M*D (8 MB)
    unsigned short* sk_b  = sq_b + (size_t)M * D;                // M*D (8 MB)
    unsigned short* v_b   = sk_b + (size_t)M * D;                // M*D (8 MB)
    unsigned short* vT    = v_b + (size_t)M * D;                 // M*D (8 MB)
    unsigned short* Sbuf2 = vT + (size_t)M * D;                  // Bv*NCH*CH*S (16.8 MB)
    unsigned short* combm = Sbuf2 + (size_t)Bv * NCH * CH * S;   // M*D (8 MB)
    float* rowscale = (float*)(combm + (size_t)M * D);           // M fp32

    dim3 blk(256);

    prep<<<8448, blk, 0, stream>>>(h, w_q, w_k, w_v, w_o, memory,
                                   h_b, wq_b, wk_b, wv_b, wo_b, memT);
    proj_fused<<<768, blk, 0, stream>>>(h_b, wq_b, wk_b, wv_b, sq_b, sk_b, v_b);
    stage2<<<2592, blk, 0, stream>>>(sq_b, sk_b, memT, v_b, mnorm, gate,
                                     combm, Sbuf2, vT, rowscale);
    pv64<<<512, blk, 0, stream>>>(Sbuf2, vT, rowscale, gate, combm);
    outproj64<<<512, blk, 0, stream>>>(combm, wo_b, out);
}

// Round 5
// 227.177 us; speedup vs baseline: 1.0914x; 1.0277x over previous
//
#include <hip/hip_runtime.h>
#include <cstddef>

#define EPSF 1e-6f

constexpr int D   = 1024;
constexpr int Bv  = 2;
constexpr int S   = 2048;
constexpr int M   = Bv * S;    // 4096
constexpr int CH  = 256;       // chunk
constexpr int NCH = S / CH;    // 8

constexpr int TSZ  = 128 * 32; // 128-row LDS tile (elems, 8 KB)
constexpr int TA64 = 64 * 32;  // 64-row LDS tile (elems, 4 KB)

typedef __attribute__((ext_vector_type(8))) short short8;   // 8 bf16
typedef __attribute__((ext_vector_type(4))) float floatx4;  // 4 fp32

__device__ __forceinline__ float elu1(float x) { return x > 0.f ? x + 1.f : __expf(x); }
__device__ __forceinline__ float sigmoidf_(float x) { return 1.f / (1.f + __expf(-x)); }
__device__ __forceinline__ unsigned short f2bf(float x) {
    unsigned u = __float_as_uint(x);
    return (unsigned short)((u + 0x7fffu + ((u >> 16) & 1u)) >> 16);
}
__device__ __forceinline__ float bf2f(unsigned short h) {
    return __uint_as_float(((unsigned)h) << 16);
}
__device__ __forceinline__ float wave_reduce(float x) {
#pragma unroll
    for (int off = 32; off > 0; off >>= 1) x += __shfl_down(x, off);
    return x;
}

// async global->LDS, 16B per lane (dest = wave-uniform base + lane*16)
__device__ __forceinline__ void gl_lds16(const unsigned short* g, unsigned short* l) {
    __builtin_amdgcn_global_load_lds(
        (const __attribute__((address_space(1))) void*)g,
        (__attribute__((address_space(3))) void*)l, 16, 0, 0);
}

// ---- r2-proven 128-tile machinery (conflicts->0, 230.3us total) ----
__device__ __forceinline__ void stage128x32(const unsigned short* g, int stride,
                                            unsigned short* lds, int wave, int lane) {
    const int t   = (wave << 6) + lane;
    const int row = t >> 2;
    const int cb  = (((t & 3) ^ ((row >> 1) & 3)) << 3);
    unsigned short* l0 = lds + (wave << 9);
    gl_lds16(g + (size_t)row * stride + cb, l0);
    gl_lds16(g + (size_t)(row + 64) * stride + cb, l0 + 2048);
}

__device__ __forceinline__ void stage64x32(const unsigned short* g, int stride,
                                           unsigned short* lds, int wave, int lane) {
    const int t   = (wave << 6) + lane;
    const int row = t >> 2;
    const int cb  = (((t & 3) ^ ((row >> 1) & 3)) << 3);
    gl_lds16(g + (size_t)row * stride + cb, lds + (wave << 9));
}

__device__ __forceinline__ void mfma_step(const unsigned short* As, const unsigned short* Bs,
                                          int wm, int wn, int fr, int g, floatx4 acc[4][4]) {
    const int off = ((g ^ ((fr >> 1) & 3)) << 3);
    short8 af[4], bf[4];
#pragma unroll
    for (int i = 0; i < 4; ++i) af[i] = *(const short8*)&As[(wm + i * 16 + fr) * 32 + off];
#pragma unroll
    for (int j = 0; j < 4; ++j) bf[j] = *(const short8*)&Bs[(wn + j * 16 + fr) * 32 + off];
#pragma unroll
    for (int i = 0; i < 4; ++i)
#pragma unroll
        for (int j = 0; j < 4; ++j)
            acc[i][j] = __builtin_amdgcn_mfma_f32_16x16x32_bf16(af[i], bf[j], acc[i][j], 0, 0, 0);
}

__device__ __forceinline__ void mfma_step64d(const unsigned short* As, const unsigned short* Bs,
                                             int wm, int wn, int fr, int g,
                                             floatx4 acc[2][4], floatx4 accd[2], short8 bones) {
    const int off = ((g ^ ((fr >> 1) & 3)) << 3);
    short8 af[2], bf[4];
#pragma unroll
    for (int i = 0; i < 2; ++i) af[i] = *(const short8*)&As[(wm + i * 16 + fr) * 32 + off];
#pragma unroll
    for (int j = 0; j < 4; ++j) bf[j] = *(const short8*)&Bs[(wn + j * 16 + fr) * 32 + off];
#pragma unroll
    for (int i = 0; i < 2; ++i) {
#pragma unroll
        for (int j = 0; j < 4; ++j)
            acc[i][j] = __builtin_amdgcn_mfma_f32_16x16x32_bf16(af[i], bf[j], acc[i][j], 0, 0, 0);
        accd[i] = __builtin_amdgcn_mfma_f32_16x16x32_bf16(af[i], bones, accd[i], 0, 0, 0);
    }
}

__device__ __forceinline__ void mfma_step64(const unsigned short* As, const unsigned short* Bs,
                                            int wm, int wn, int fr, int g, floatx4 acc[2][4]) {
    const int off = ((g ^ ((fr >> 1) & 3)) << 3);
    short8 af[2], bf[4];
#pragma unroll
    for (int i = 0; i < 2; ++i) af[i] = *(const short8*)&As[(wm + i * 16 + fr) * 32 + off];
#pragma unroll
    for (int j = 0; j < 4; ++j) bf[j] = *(const short8*)&Bs[(wn + j * 16 + fr) * 32 + off];
#pragma unroll
    for (int i = 0; i < 2; ++i)
#pragma unroll
        for (int j = 0; j < 4; ++j)
            acc[i][j] = __builtin_amdgcn_mfma_f32_16x16x32_bf16(af[i], bf[j], acc[i][j], 0, 0, 0);
}

__device__ __forceinline__ void gemm_loop_db(const unsigned short* Ag, int strideA,
                                             const unsigned short* Bg, int strideB, int Kk,
                                             unsigned short* As, unsigned short* Bs,
                                             int wave, int lane, int wm, int wn, int fr, int g,
                                             floatx4 acc[4][4]) {
    __syncthreads();
    stage128x32(Ag, strideA, As, wave, lane);
    stage128x32(Bg, strideB, Bs, wave, lane);
    int buf = 0;
    for (int k0 = 32; k0 < Kk; k0 += 32) {
        __syncthreads();
        const int nb = buf ^ 1;
        stage128x32(Ag + k0, strideA, As + nb * TSZ, wave, lane);
        stage128x32(Bg + k0, strideB, Bs + nb * TSZ, wave, lane);
        mfma_step(As + buf * TSZ, Bs + buf * TSZ, wm, wn, fr, g, acc);
        buf = nb;
    }
    __syncthreads();
    mfma_step(As + buf * TSZ, Bs + buf * TSZ, wm, wn, fr, g, acc);
}

__device__ __forceinline__ void gemm_loop_db64d(const unsigned short* Ag, int strideA,
                                                const unsigned short* Bg, int strideB, int Kk,
                                                unsigned short* As, unsigned short* Bs,
                                                int wave, int lane, int wm, int wn, int fr, int g,
                                                floatx4 acc[2][4], floatx4 accd[2], short8 bones) {
    __syncthreads();
    stage64x32(Ag, strideA, As, wave, lane);
    stage128x32(Bg, strideB, Bs, wave, lane);
    int buf = 0;
    for (int k0 = 32; k0 < Kk; k0 += 32) {
        __syncthreads();
        const int nb = buf ^ 1;
        stage64x32(Ag + k0, strideA, As + nb * TA64, wave, lane);
        stage128x32(Bg + k0, strideB, Bs + nb * TSZ, wave, lane);
        mfma_step64d(As + buf * TA64, Bs + buf * TSZ, wm, wn, fr, g, acc, accd, bones);
        buf = nb;
    }
    __syncthreads();
    mfma_step64d(As + buf * TA64, Bs + buf * TSZ, wm, wn, fr, g, acc, accd, bones);
}

__device__ __forceinline__ void gemm_loop_db64(const unsigned short* Ag, int strideA,
                                               const unsigned short* Bg, int strideB, int Kk,
                                               unsigned short* As, unsigned short* Bs,
                                               int wave, int lane, int wm, int wn, int fr, int g,
                                               floatx4 acc[2][4]) {
    __syncthreads();
    stage64x32(Ag, strideA, As, wave, lane);
    stage128x32(Bg, strideB, Bs, wave, lane);
    int buf = 0;
    for (int k0 = 32; k0 < Kk; k0 += 32) {
        __syncthreads();
        const int nb = buf ^ 1;
        stage64x32(Ag + k0, strideA, As + nb * TA64, wave, lane);
        stage128x32(Bg + k0, strideB, Bs + nb * TSZ, wave, lane);
        mfma_step64(As + buf * TA64, Bs + buf * TSZ, wm, wn, fr, g, acc);
        buf = nb;
    }
    __syncthreads();
    mfma_step64(As + buf * TA64, Bs + buf * TSZ, wm, wn, fr, g, acc);
}

// ---------------- prep: cvt h + cvt 4 weights + transpose memory ----------------
__global__ __launch_bounds__(256) void prep(const float* __restrict__ h,
                                            const float* __restrict__ w_q, const float* __restrict__ w_k,
                                            const float* __restrict__ w_v, const float* __restrict__ w_o,
                                            const float* __restrict__ memory,
                                            unsigned short* __restrict__ h_b,
                                            unsigned short* __restrict__ wq_b, unsigned short* __restrict__ wk_b,
                                            unsigned short* __restrict__ wv_b, unsigned short* __restrict__ wo_b,
                                            unsigned short* __restrict__ memT)
{
    __shared__ unsigned short T[64][72];
    const int id = blockIdx.x, tid = threadIdx.x;
    if (id < 4096) {
        const size_t i = ((size_t)id * 256 + tid) * 4;
        float4 v = *(const float4*)(h + i);
        ushort4 o; o.x = f2bf(v.x); o.y = f2bf(v.y); o.z = f2bf(v.z); o.w = f2bf(v.w);
        *(ushort4*)(h_b + i) = o;
    } else if (id < 8192) {
        const int t = id - 4096, which = t >> 10;
        const float* in = (which == 0) ? w_q : (which == 1) ? w_k : (which == 2) ? w_v : w_o;
        unsigned short* out = (which == 0) ? wq_b : (which == 1) ? wk_b : (which == 2) ? wv_b : wo_b;
        const size_t i = ((size_t)(t & 1023) * 256 + tid) * 4;
        float4 v = *(const float4*)(in + i);
        ushort4 o; o.x = f2bf(v.x); o.y = f2bf(v.y); o.z = f2bf(v.z); o.w = f2bf(v.w);
        *(ushort4*)(out + i) = o;
    } else {
        const int t = id - 8192;
        const int d0 = (t >> 4) * 64, e0 = (t & 15) * 64;
        const int r = tid >> 4, c4 = (tid & 15) * 4;
        for (int rr = r; rr < 64; rr += 16) {
            float4 v = *(const float4*)(memory + (size_t)(d0 + rr) * D + e0 + c4);
            T[rr][c4 + 0] = f2bf(v.x); T[rr][c4 + 1] = f2bf(v.y);
            T[rr][c4 + 2] = f2bf(v.z); T[rr][c4 + 3] = f2bf(v.w);
        }
        __syncthreads();
        for (int rr = r; rr < 64; rr += 16) {
            ushort4 o;
            o.x = T[c4 + 0][rr]; o.y = T[c4 + 1][rr];
            o.z = T[c4 + 2][rr]; o.w = T[c4 + 3][rr];
            *(ushort4*)(memT + (size_t)(e0 + rr) * D + d0 + c4) = o;
        }
    }
}

// ---------------- proj8: q/k/v projections, 256x256 tile, 8-wave deep pipeline ----------------
// T3+T4 port (r5): per-phase {ds_read || 1 half-tile stage -> barrier -> setprio+16 MFMA -> barrier},
// counted vmcnt(4) once per K-tile (never 0 in the loop). Halves: A0/A1/B0/B1 (128x64 bf16, 16KB).
// Schedule: phases 0/1 stage A0/A1(tile u+1) into other buffer (released by tile u-1's end barrier);
// phases 2/3 stage B0/B1(tile u+2) into current buffer (B fully consumed at phase 0).
// In-order vmcnt: vmcnt(4) at phase 3 => all of tile u+1 resident, B(u+2) still in flight.
__global__ __launch_bounds__(512, 2) void proj8(const unsigned short* __restrict__ h_b,
                                                const unsigned short* __restrict__ wq,
                                                const unsigned short* __restrict__ wk,
                                                const unsigned short* __restrict__ wv,
                                                unsigned short* __restrict__ sq,
                                                unsigned short* __restrict__ sk,
                                                unsigned short* __restrict__ v)
{
    extern __shared__ unsigned short sm[];   // 2 buf x 4 halves x 8192 elems = 128 KB
    const int id = blockIdx.x;
    const int x = id & 7, y = id >> 3;       // y 0..23
    const int strip = x + 8 * (y % 6);       // 0..47 ; 4 n-tiles of a strip share XCD
    const int nn = y / 6;                    // 0..3
    const int sub = strip >> 4, m = strip & 15;
    const int m0 = m * 256, n0 = nn * 256;
    const unsigned short* Ag = h_b + (size_t)m0 * D;
    const unsigned short* Bg = ((sub == 0) ? wq : (sub == 1) ? wk : wv) + (size_t)n0 * D;
    unsigned short* C = (sub == 0) ? sq : (sub == 1) ? sk : v;

    const int tid = threadIdx.x;
    const int w = tid >> 6, lane = tid & 63;
    const int wr = w >> 2, wc = w & 3;       // 2M x 4N waves, per-wave 128x64 output
    const int fr = lane & 15, gq = lane >> 4;
    const int swz = fr & 7;

    // staging precompute: half-tile = 1024 x 16B chunks; 2 chunks/thread
    const int r0 = tid >> 3;
    const int c0 = (tid & 7) ^ (r0 & 7);            // pre-swizzled source chunk
    const int r1 = (tid + 512) >> 3;
    const int c1 = ((tid + 512) & 7) ^ (r1 & 7);
    const size_t so0 = (size_t)r0 * D + (size_t)c0 * 8;
    const size_t so1 = (size_t)r1 * D + (size_t)c1 * 8;
    unsigned short* const dst0 = sm + tid * 8;       // + slot base: lane*16B within wave block
    unsigned short* const dst1 = sm + (tid + 512) * 8;

    floatx4 acc[8][4] = {};

#define STG(kt, b, which) do {                                                      \
        const unsigned short* Gs = ((which) < 2 ? Ag : Bg)                          \
            + (size_t)(((which) & 1) * 128) * D + (size_t)(kt) * 64;                \
        const int slot = (((b) << 2) + (which)) << 13;                              \
        gl_lds16(Gs + so0, dst0 + slot);                                            \
        gl_lds16(Gs + so1, dst1 + slot);                                            \
    } while (0)

    // prologue: tile0 fully + B halves of tile1 (12 loads); drain to 4 (B(1) stays in flight)
    STG(0, 0, 0); STG(0, 0, 1); STG(0, 0, 2); STG(0, 0, 3);
    STG(1, 1, 2); STG(1, 1, 3);
    asm volatile("s_waitcnt vmcnt(4)" ::: "memory");
    __builtin_amdgcn_s_barrier();

    const int NT = D / 64;  // 16 K-tiles
    for (int u = 0; u < NT; ++u) {
        const int bu = u & 1;
        const unsigned short* Ah = sm + (((bu << 2) + wr) << 13);
        const unsigned short* Bh = sm + (((bu << 2) + 2 + (wc >> 1)) << 13);
        const int brow = (wc & 1) * 64;
        short8 bfr[4][2];
#pragma unroll
        for (int s = 0; s < 4; ++s) {
            short8 afr[2][2];
#pragma unroll
            for (int i2 = 0; i2 < 2; ++i2)
#pragma unroll
                for (int ks = 0; ks < 2; ++ks)
                    afr[i2][ks] = *(const short8*)&Ah[((s * 2 + i2) * 16 + fr) * 64
                                                      + ((((ks << 2) + gq) ^ swz) << 3)];
            if (s == 0) {
#pragma unroll
                for (int j = 0; j < 4; ++j)
#pragma unroll
                    for (int ks = 0; ks < 2; ++ks)
                        bfr[j][ks] = *(const short8*)&Bh[(brow + j * 16 + fr) * 64
                                                         + ((((ks << 2) + gq) ^ swz) << 3)];
            }
            if (s == 0)      { if (u + 1 < NT) STG(u + 1, bu ^ 1, 0); }
            else if (s == 1) { if (u + 1 < NT) STG(u + 1, bu ^ 1, 1); }
            else if (s == 2) { if (u + 2 < NT) STG(u + 2, bu, 2); }
            else {
                if (u + 2 < NT) {
                    STG(u + 2, bu, 3);
                    asm volatile("s_waitcnt vmcnt(4)" ::: "memory");   // counted: B(u+2) stays in flight
                } else if (u + 1 < NT) {
                    asm volatile("s_waitcnt vmcnt(0)" ::: "memory");   // epilogue drain
                }
            }
            __builtin_amdgcn_s_barrier();
            __builtin_amdgcn_s_setprio(1);
#pragma unroll
            for (int i2 = 0; i2 < 2; ++i2)
#pragma unroll
                for (int j = 0; j < 4; ++j)
#pragma unroll
                    for (int ks = 0; ks < 2; ++ks)
                        acc[s * 2 + i2][j] = __builtin_amdgcn_mfma_f32_16x16x32_bf16(
                            afr[i2][ks], bfr[j][ks], acc[s * 2 + i2][j], 0, 0, 0);
            __builtin_amdgcn_s_setprio(0);
            __builtin_amdgcn_s_barrier();
        }
    }
#undef STG

    const int q4 = gq * 4;
#pragma unroll
    for (int i = 0; i < 8; ++i)
#pragma unroll
        for (int j = 0; j < 4; ++j) {
            const int col = n0 + wc * 64 + j * 16 + fr;
#pragma unroll
            for (int r = 0; r < 4; ++r) {
                const int row = m0 + wr * 128 + i * 16 + q4 + r;
                float val = acc[i][j][r];
                if (sub < 2) val = elu1(val);
                C[(size_t)row * D + col] = f2bf(val);
            }
        }
}

// ---------------- fused q/k/v projections (r2 fallback, 128-tile) ----------------
__global__ __launch_bounds__(256) void proj_fused(const unsigned short* __restrict__ h_b,
                                                  const unsigned short* __restrict__ wq,
                                                  const unsigned short* __restrict__ wk,
                                                  const unsigned short* __restrict__ wv,
                                                  unsigned short* __restrict__ sq,
                                                  unsigned short* __restrict__ sk,
                                                  unsigned short* __restrict__ v)
{
    __shared__ unsigned short As[2 * TSZ], Bs[2 * TSZ];
    const int id = blockIdx.x;
    const int x = id & 7, y = id >> 3;
    const int strip = x + 8 * (y % 12);
    const int n     = y / 12;
    const int sub = strip >> 5, m = strip & 31;
    const int m0 = m * 128, n0 = n * 128;
    const unsigned short* B = (sub == 0) ? wq : (sub == 1) ? wk : wv;
    unsigned short* C = (sub == 0) ? sq : (sub == 1) ? sk : v;

    const int tid = threadIdx.x, wave = tid >> 6, lane = tid & 63;
    const int wm = (wave >> 1) * 64, wn = (wave & 1) * 64;
    const int fr = lane & 15, g = lane >> 4;
    const int q4 = g * 4;

    floatx4 acc[4][4] = {};
    gemm_loop_db(h_b + (size_t)m0 * D, D, B + (size_t)n0 * D, D, D,
                 As, Bs, wave, lane, wm, wn, fr, g, acc);

#pragma unroll
    for (int i = 0; i < 4; ++i)
#pragma unroll
        for (int j = 0; j < 4; ++j) {
            const int col = n0 + wn + j * 16 + fr;
#pragma unroll
            for (int r = 0; r < 4; ++r) {
                const int row = m0 + wm + i * 16 + q4 + r;
                float val = acc[i][j][r];
                if (sub < 2) val = elu1(val);
                C[(size_t)row * D + col] = f2bf(val);
            }
        }
}

// ---------------- stage2: memgemm(256) + scores(288) + v-transpose(1024) + rowscale(1024)
__global__ __launch_bounds__(256) void stage2(const unsigned short* __restrict__ sq,
                                              const unsigned short* __restrict__ sk,
                                              const unsigned short* __restrict__ memT,
                                              const unsigned short* __restrict__ v_b,
                                              const float* __restrict__ mnorm,
                                              const float* __restrict__ gate,
                                              unsigned short* __restrict__ combm,
                                              unsigned short* __restrict__ Sbuf2,
                                              unsigned short* __restrict__ vT,
                                              float* __restrict__ rowscale)
{
    __shared__ unsigned short As[2 * TSZ], Bs[2 * TSZ];
    const int id = blockIdx.x, tid = threadIdx.x;
    const int wave = tid >> 6, lane = tid & 63;
    const int wm = (wave >> 1) * 64, wn = (wave & 1) * 64;
    const int fr = lane & 15, g = lane >> 4;
    const int q4 = g * 4;

    if (id < 256) {
        const int x = id & 7, y = id >> 3;
        const int m0 = (x + 8 * (y & 3)) * 128;
        const int n0 = (y >> 2) * 128;
        floatx4 acc[4][4] = {};
        gemm_loop_db(sq + (size_t)m0 * D, D, memT + (size_t)n0 * D, D, D,
                     As, Bs, wave, lane, wm, wn, fr, g, acc);
#pragma unroll
        for (int i = 0; i < 4; ++i)
#pragma unroll
            for (int j = 0; j < 4; ++j) {
                const int col = n0 + wn + j * 16 + fr;
#pragma unroll
                for (int r = 0; r < 4; ++r)
                    combm[(size_t)(m0 + wm + i * 16 + q4 + r) * D + col] = f2bf(acc[i][j][r]);
            }
    } else if (id < 544) {
        const int t = id - 256;
        const int b = t / 144, rem = t % 144;
        const int p = rem >> 2, tt = rem & 3;
        const int it = tt >> 1, jt = tt & 1;
        int c = 0;
        while ((c + 1) * (c + 2) / 2 <= p) ++c;
        const int j = p - c * (c + 1) / 2;
        unsigned short* Srow0 = Sbuf2 + (size_t)(b * NCH + c) * CH * S;

        if (j == c && jt > it) {
            const int row = it * 128 + (tid >> 1);
            unsigned short* zp = Srow0 + (size_t)row * S + j * CH + jt * 128 + (tid & 1) * 64;
            uint4 z4 = make_uint4(0, 0, 0, 0);
#pragma unroll
            for (int i = 0; i < 8; ++i) *(uint4*)(zp + i * 8) = z4;
            return;
        }
        floatx4 acc[4][4] = {};
        gemm_loop_db(sq + ((size_t)b * S + (size_t)c * CH + it * 128) * D, D,
                     sk + ((size_t)b * S + (size_t)j * CH + jt * 128) * D, D, D,
                     As, Bs, wave, lane, wm, wn, fr, g, acc);
        const bool diag = (j == c && it == jt);
#pragma unroll
        for (int i = 0; i < 4; ++i)
#pragma unroll
            for (int jj = 0; jj < 4; ++jj) {
                const int col = jt * 128 + wn + jj * 16 + fr;
#pragma unroll
                for (int r = 0; r < 4; ++r) {
                    const int row = it * 128 + wm + i * 16 + q4 + r;
                    float val = acc[i][jj][r];
                    if (diag && col > row) val = 0.f;
                    Srow0[(size_t)row * S + j * CH + col] = f2bf(val);
                }
            }
    } else if (id < 1568) {
        unsigned short (*T)[72] = (unsigned short(*)[72])As;
        const int t = id - 544;
        const int b = t >> 9, rem = t & 511;
        const int s0 = (rem >> 4) * 64, d0 = (rem & 15) * 64;
        const int r = tid >> 4, c4 = (tid & 15) * 4;
        const unsigned short* ip = v_b + (size_t)b * S * D;
        for (int rr = r; rr < 64; rr += 16) {
            ushort4 vv = *(const ushort4*)(ip + (size_t)(s0 + rr) * D + d0 + c4);
            T[rr][c4 + 0] = vv.x; T[rr][c4 + 1] = vv.y; T[rr][c4 + 2] = vv.z; T[rr][c4 + 3] = vv.w;
        }
        __syncthreads();
        unsigned short* op = vT + (size_t)b * D * S;
        for (int rr = r; rr < 64; rr += 16) {
            ushort4 o;
            o.x = T[c4 + 0][rr]; o.y = T[c4 + 1][rr];
            o.z = T[c4 + 2][rr]; o.w = T[c4 + 3][rr];
            *(ushort4*)(op + (size_t)(d0 + rr) * S + s0 + c4) = o;
        }
    } else {
        const int row = (id - 1568) * 4 + wave;
        const unsigned short* sr = sq + (size_t)row * D;
        float dot = 0.f, msum = 0.f;
#pragma unroll
        for (int p = 0; p < 2; ++p) {
            const int d0 = p * 512 + lane * 8;
            short8 sv = *(const short8*)(sr + d0);
            float4 m0 = *(const float4*)(mnorm + d0);
            float4 m1 = *(const float4*)(mnorm + d0 + 4);
            dot += bf2f((unsigned short)sv[0]) * m0.x + bf2f((unsigned short)sv[1]) * m0.y
                 + bf2f((unsigned short)sv[2]) * m0.z + bf2f((unsigned short)sv[3]) * m0.w
                 + bf2f((unsigned short)sv[4]) * m1.x + bf2f((unsigned short)sv[5]) * m1.y
                 + bf2f((unsigned short)sv[6]) * m1.z + bf2f((unsigned short)sv[7]) * m1.w;
            msum += m0.x + m0.y + m0.z + m0.w + m1.x + m1.y + m1.z + m1.w;
        }
        dot = wave_reduce(dot);
        msum = wave_reduce(msum);
        if (lane == 0) {
            const float gg = sigmoidf_(gate[0]);
            const float active = (msum >= EPSF) ? 1.f : 0.f;
            rowscale[row] = gg * active / fmaxf(dot, EPSF);
        }
    }
}

// ---------------- pv ----------------
__global__ __launch_bounds__(256) void pv64(const unsigned short* __restrict__ Sbuf2,
                                            const unsigned short* __restrict__ vT,
                                            const float* __restrict__ rowscale,
                                            const float* __restrict__ gate,
                                            unsigned short* __restrict__ combm)
{
    __shared__ unsigned short As2[2 * TA64], Bs2[2 * TSZ];
    const int id = blockIdx.x, tid = threadIdx.x;
    const int wave = tid >> 6, lane = tid & 63;
    const int wm = (wave >> 1) * 32, wn = (wave & 1) * 64;
    const int fr = lane & 15, g = lane >> 4;
    const int q4 = g * 4;

    const int x = id & 7, y = id >> 3;
    const int g_ = x + 8 * (y & 7);
    const int e  = y >> 3;
    const int b = g_ >> 5;
    const int rem = g_ & 31;
    const int c = (NCH - 1) - (rem >> 2);
    const int i0 = (rem & 3) * 64, e0 = e * 128;

    const short one_bf = (short)0x3F80;
    short8 bones = {one_bf, one_bf, one_bf, one_bf, one_bf, one_bf, one_bf, one_bf};

    floatx4 acc[2][4] = {};
    floatx4 accd[2] = {};
    gemm_loop_db64d(Sbuf2 + ((size_t)(b * NCH + c) * CH + i0) * S, S,
                    vT + (size_t)b * D * S + (size_t)e0 * S, S, (c + 1) * CH,
                    As2, Bs2, wave, lane, wm, wn, fr, g, acc, accd, bones);

    const float gg = sigmoidf_(gate[0]);
    const float wloc = 1.f - gg;
#pragma unroll
    for (int i = 0; i < 2; ++i)
#pragma unroll
        for (int j = 0; j < 4; ++j) {
            const int col = e0 + wn + j * 16 + fr;
#pragma unroll
            for (int r = 0; r < 4; ++r) {
                const int li = i0 + wm + i * 16 + q4 + r;
                const int rg = b * S + c * CH + li;
                const float inv = wloc / fmaxf(accd[i][r], EPSF);
                const size_t idx = (size_t)rg * D + col;
                combm[idx] = f2bf(bf2f(combm[idx]) * rowscale[rg] + acc[i][j][r] * inv);
            }
        }
}

// ---------------- out-proj ----------------
__global__ __launch_bounds__(256) void outproj64(const unsigned short* __restrict__ A,
                                                 const unsigned short* __restrict__ wo,
                                                 float* __restrict__ out)
{
    __shared__ unsigned short As2[2 * TA64], Bs2[2 * TSZ];
    const int id = blockIdx.x, tid = threadIdx.x;
    const int wave = tid >> 6, lane = tid & 63;
    const int wm = (wave >> 1) * 32, wn = (wave & 1) * 64;
    const int fr = lane & 15, g = lane >> 4;
    const int q4 = g * 4;

    const int x = id & 7, y = id >> 3;
    const int m0 = (x + 8 * (y & 7)) * 64;
    const int n0 = (y >> 3) * 128;

    floatx4 acc[2][4] = {};
    gemm_loop_db64(A + (size_t)m0 * D, D, wo + (size_t)n0 * D, D, D,
                   As2, Bs2, wave, lane, wm, wn, fr, g, acc);

#pragma unroll
    for (int i = 0; i < 2; ++i)
#pragma unroll
        for (int j = 0; j < 4; ++j) {
            const int col = n0 + wn + j * 16 + fr;
#pragma unroll
            for (int r = 0; r < 4; ++r)
                out[(size_t)(m0 + wm + i * 16 + q4 + r) * D + col] = acc[i][j][r];
        }
}

extern "C" void kernel_launch(void* const* d_in, const int* in_sizes, int n_in,
                              void* d_out, int out_size, void* d_ws, size_t ws_size,
                              hipStream_t stream)
{
    const float* h      = (const float*)d_in[0];
    const float* w_q    = (const float*)d_in[1];
    const float* w_k    = (const float*)d_in[2];
    const float* w_v    = (const float*)d_in[3];
    const float* w_o    = (const float*)d_in[4];
    const float* gate   = (const float*)d_in[5];
    const float* memory = (const float*)d_in[6];
    const float* mnorm  = (const float*)d_in[7];
    float* out = (float*)d_out;

    unsigned short* h_b   = (unsigned short*)d_ws;               // M*D (8 MB)
    unsigned short* wq_b  = h_b + (size_t)M * D;                 // D*D
    unsigned short* wk_b  = wq_b + (size_t)D * D;                // D*D
    unsigned short* wv_b  = wk_b + (size_t)D * D;                // D*D
    unsigned short* wo_b  = wv_b + (size_t)D * D;                // D*D
    unsigned short* memT  = wo_b + (size_t)D * D;                // D*D (2 MB)
    unsigned short* sq_b  = memT + (size_t)D * D;                // M*D (8 MB)
    unsigned short* sk_b  = sq_b + (size_t)M * D;                // M*D (8 MB)
    unsigned short* v_b   = sk_b + (size_t)M * D;                // M*D (8 MB)
    unsigned short* vT    = v_b + (size_t)M * D;                 // M*D (8 MB)
    unsigned short* Sbuf2 = vT + (size_t)M * D;                  // Bv*NCH*CH*S (16.8 MB)
    unsigned short* combm = Sbuf2 + (size_t)Bv * NCH * CH * S;   // M*D (8 MB)
    float* rowscale = (float*)(combm + (size_t)M * D);           // M fp32

    dim3 blk(256);

    prep<<<8448, blk, 0, stream>>>(h, w_q, w_k, w_v, w_o, memory,
                                   h_b, wq_b, wk_b, wv_b, wo_b, memT);

    // 128 KB dynamic LDS for proj8; fall back to proven 128-tile kernel if unsupported
    static const bool proj8_ok = [] {
        return hipFuncSetAttribute(reinterpret_cast<const void*>(proj8),
                                   hipFuncAttributeMaxDynamicSharedMemorySize,
                                   131072) == hipSuccess;
    }();
    if (proj8_ok)
        proj8<<<192, dim3(512), 131072, stream>>>(h_b, wq_b, wk_b, wv_b, sq_b, sk_b, v_b);
    else
        proj_fused<<<768, blk, 0, stream>>>(h_b, wq_b, wk_b, wv_b, sq_b, sk_b, v_b);

    stage2<<<2592, blk, 0, stream>>>(sq_b, sk_b, memT, v_b, mnorm, gate,
                                     combm, Sbuf2, vT, rowscale);
    pv64<<<512, blk, 0, stream>>>(Sbuf2, vT, rowscale, gate, combm);
    outproj64<<<512, blk, 0, stream>>>(combm, wo_b, out);
}

// Round 6
// 218.391 us; speedup vs baseline: 1.1353x; 1.0402x over previous
//
#include <hip/hip_runtime.h>
#include <cstddef>

#define EPSF 1e-6f

constexpr int D   = 1024;
constexpr int Bv  = 2;
constexpr int S   = 2048;
constexpr int M   = Bv * S;    // 4096
constexpr int CH  = 256;       // chunk
constexpr int NCH = S / CH;    // 8

constexpr int TSZ  = 128 * 32; // 128-row LDS tile (elems, 8 KB)
constexpr int TA64 = 64 * 32;  // 64-row LDS tile (elems, 4 KB)

typedef __attribute__((ext_vector_type(8))) short short8;   // 8 bf16
typedef __attribute__((ext_vector_type(4))) float floatx4;  // 4 fp32

__device__ __forceinline__ float elu1(float x) { return x > 0.f ? x + 1.f : __expf(x); }
__device__ __forceinline__ float sigmoidf_(float x) { return 1.f / (1.f + __expf(-x)); }
__device__ __forceinline__ unsigned short f2bf(float x) {
    unsigned u = __float_as_uint(x);
    return (unsigned short)((u + 0x7fffu + ((u >> 16) & 1u)) >> 16);
}
__device__ __forceinline__ float bf2f(unsigned short h) {
    return __uint_as_float(((unsigned)h) << 16);
}
__device__ __forceinline__ float wave_reduce(float x) {
#pragma unroll
    for (int off = 32; off > 0; off >>= 1) x += __shfl_down(x, off);
    return x;
}

// async global->LDS, 16B per lane (dest = wave-uniform base + lane*16)
__device__ __forceinline__ void gl_lds16(const unsigned short* g, unsigned short* l) {
    __builtin_amdgcn_global_load_lds(
        (const __attribute__((address_space(1))) void*)g,
        (__attribute__((address_space(3))) void*)l, 16, 0, 0);
}

// ==================== 256x256 8-phase deep-pipeline core (r5 HW-verified) ====================
// Per-phase {ds_read || 1 half-tile stage -> barrier -> setprio+16 MFMA -> barrier},
// counted vmcnt(4) once per K-tile (never 0 in the loop). A/B stride = D, K = D (NT=16).
__device__ __forceinline__ void gemm256_8ph(const unsigned short* __restrict__ Ag,
                                            const unsigned short* __restrict__ Bg,
                                            unsigned short* sm, int tid,
                                            floatx4 acc[8][4]) {
    const int lane = tid & 63, w = tid >> 6;
    const int wr = w >> 2, wc = w & 3;       // 2M x 4N waves, per-wave 128x64 output
    const int fr = lane & 15, gq = lane >> 4;
    const int swz = fr & 7;

    const int r0 = tid >> 3;
    const int c0 = (tid & 7) ^ (r0 & 7);            // pre-swizzled source chunk
    const int r1 = (tid + 512) >> 3;
    const int c1 = ((tid + 512) & 7) ^ (r1 & 7);
    const size_t so0 = (size_t)r0 * D + (size_t)c0 * 8;
    const size_t so1 = (size_t)r1 * D + (size_t)c1 * 8;
    unsigned short* const dst0 = sm + tid * 8;
    unsigned short* const dst1 = sm + (tid + 512) * 8;

    auto STG = [&](int kt, int b, int which) {
        const unsigned short* Gs = ((which) < 2 ? Ag : Bg)
            + (size_t)(((which) & 1) * 128) * D + (size_t)(kt) * 64;
        const int slot = (((b) << 2) + (which)) << 13;
        gl_lds16(Gs + so0, dst0 + slot);
        gl_lds16(Gs + so1, dst1 + slot);
    };

    // prologue: tile0 fully + B halves of tile1; drain to 4 (B(1) stays in flight)
    STG(0, 0, 0); STG(0, 0, 1); STG(0, 0, 2); STG(0, 0, 3);
    STG(1, 1, 2); STG(1, 1, 3);
    asm volatile("s_waitcnt vmcnt(4)" ::: "memory");
    __builtin_amdgcn_s_barrier();

    const int NT = D / 64;  // 16 K-tiles
    for (int u = 0; u < NT; ++u) {
        const int bu = u & 1;
        const unsigned short* Ah = sm + (((bu << 2) + wr) << 13);
        const unsigned short* Bh = sm + (((bu << 2) + 2 + (wc >> 1)) << 13);
        const int brow = (wc & 1) * 64;
        short8 bfr[4][2];
#pragma unroll
        for (int s = 0; s < 4; ++s) {
            short8 afr[2][2];
#pragma unroll
            for (int i2 = 0; i2 < 2; ++i2)
#pragma unroll
                for (int ks = 0; ks < 2; ++ks)
                    afr[i2][ks] = *(const short8*)&Ah[((s * 2 + i2) * 16 + fr) * 64
                                                      + ((((ks << 2) + gq) ^ swz) << 3)];
            if (s == 0) {
#pragma unroll
                for (int j = 0; j < 4; ++j)
#pragma unroll
                    for (int ks = 0; ks < 2; ++ks)
                        bfr[j][ks] = *(const short8*)&Bh[(brow + j * 16 + fr) * 64
                                                         + ((((ks << 2) + gq) ^ swz) << 3)];
            }
            if (s == 0)      { if (u + 1 < NT) STG(u + 1, bu ^ 1, 0); }
            else if (s == 1) { if (u + 1 < NT) STG(u + 1, bu ^ 1, 1); }
            else if (s == 2) { if (u + 2 < NT) STG(u + 2, bu, 2); }
            else {
                if (u + 2 < NT) {
                    STG(u + 2, bu, 3);
                    asm volatile("s_waitcnt vmcnt(4)" ::: "memory");   // counted: never 0 in loop
                } else if (u + 1 < NT) {
                    asm volatile("s_waitcnt vmcnt(0)" ::: "memory");   // epilogue drain
                }
            }
            __builtin_amdgcn_s_barrier();
            __builtin_amdgcn_s_setprio(1);
#pragma unroll
            for (int i2 = 0; i2 < 2; ++i2)
#pragma unroll
                for (int j = 0; j < 4; ++j)
#pragma unroll
                    for (int ks = 0; ks < 2; ++ks)
                        acc[s * 2 + i2][j] = __builtin_amdgcn_mfma_f32_16x16x32_bf16(
                            afr[i2][ks], bfr[j][ks], acc[s * 2 + i2][j], 0, 0, 0);
            __builtin_amdgcn_s_setprio(0);
            __builtin_amdgcn_s_barrier();
        }
    }
}

// ---- r2-proven 128-tile machinery (fallback path) ----
__device__ __forceinline__ void stage128x32(const unsigned short* g, int stride,
                                            unsigned short* lds, int wave, int lane) {
    const int t   = (wave << 6) + lane;
    const int row = t >> 2;
    const int cb  = (((t & 3) ^ ((row >> 1) & 3)) << 3);
    unsigned short* l0 = lds + (wave << 9);
    gl_lds16(g + (size_t)row * stride + cb, l0);
    gl_lds16(g + (size_t)(row + 64) * stride + cb, l0 + 2048);
}

__device__ __forceinline__ void stage64x32(const unsigned short* g, int stride,
                                           unsigned short* lds, int wave, int lane) {
    const int t   = (wave << 6) + lane;
    const int row = t >> 2;
    const int cb  = (((t & 3) ^ ((row >> 1) & 3)) << 3);
    gl_lds16(g + (size_t)row * stride + cb, lds + (wave << 9));
}

__device__ __forceinline__ void mfma_step(const unsigned short* As, const unsigned short* Bs,
                                          int wm, int wn, int fr, int g, floatx4 acc[4][4]) {
    const int off = ((g ^ ((fr >> 1) & 3)) << 3);
    short8 af[4], bf[4];
#pragma unroll
    for (int i = 0; i < 4; ++i) af[i] = *(const short8*)&As[(wm + i * 16 + fr) * 32 + off];
#pragma unroll
    for (int j = 0; j < 4; ++j) bf[j] = *(const short8*)&Bs[(wn + j * 16 + fr) * 32 + off];
#pragma unroll
    for (int i = 0; i < 4; ++i)
#pragma unroll
        for (int j = 0; j < 4; ++j)
            acc[i][j] = __builtin_amdgcn_mfma_f32_16x16x32_bf16(af[i], bf[j], acc[i][j], 0, 0, 0);
}

__device__ __forceinline__ void mfma_step64d(const unsigned short* As, const unsigned short* Bs,
                                             int wm, int wn, int fr, int g,
                                             floatx4 acc[2][4], floatx4 accd[2], short8 bones) {
    const int off = ((g ^ ((fr >> 1) & 3)) << 3);
    short8 af[2], bf[4];
#pragma unroll
    for (int i = 0; i < 2; ++i) af[i] = *(const short8*)&As[(wm + i * 16 + fr) * 32 + off];
#pragma unroll
    for (int j = 0; j < 4; ++j) bf[j] = *(const short8*)&Bs[(wn + j * 16 + fr) * 32 + off];
#pragma unroll
    for (int i = 0; i < 2; ++i) {
#pragma unroll
        for (int j = 0; j < 4; ++j)
            acc[i][j] = __builtin_amdgcn_mfma_f32_16x16x32_bf16(af[i], bf[j], acc[i][j], 0, 0, 0);
        accd[i] = __builtin_amdgcn_mfma_f32_16x16x32_bf16(af[i], bones, accd[i], 0, 0, 0);
    }
}

__device__ __forceinline__ void mfma_step64(const unsigned short* As, const unsigned short* Bs,
                                            int wm, int wn, int fr, int g, floatx4 acc[2][4]) {
    const int off = ((g ^ ((fr >> 1) & 3)) << 3);
    short8 af[2], bf[4];
#pragma unroll
    for (int i = 0; i < 2; ++i) af[i] = *(const short8*)&As[(wm + i * 16 + fr) * 32 + off];
#pragma unroll
    for (int j = 0; j < 4; ++j) bf[j] = *(const short8*)&Bs[(wn + j * 16 + fr) * 32 + off];
#pragma unroll
    for (int i = 0; i < 2; ++i)
#pragma unroll
        for (int j = 0; j < 4; ++j)
            acc[i][j] = __builtin_amdgcn_mfma_f32_16x16x32_bf16(af[i], bf[j], acc[i][j], 0, 0, 0);
}

__device__ __forceinline__ void gemm_loop_db(const unsigned short* Ag, int strideA,
                                             const unsigned short* Bg, int strideB, int Kk,
                                             unsigned short* As, unsigned short* Bs,
                                             int wave, int lane, int wm, int wn, int fr, int g,
                                             floatx4 acc[4][4]) {
    __syncthreads();
    stage128x32(Ag, strideA, As, wave, lane);
    stage128x32(Bg, strideB, Bs, wave, lane);
    int buf = 0;
    for (int k0 = 32; k0 < Kk; k0 += 32) {
        __syncthreads();
        const int nb = buf ^ 1;
        stage128x32(Ag + k0, strideA, As + nb * TSZ, wave, lane);
        stage128x32(Bg + k0, strideB, Bs + nb * TSZ, wave, lane);
        mfma_step(As + buf * TSZ, Bs + buf * TSZ, wm, wn, fr, g, acc);
        buf = nb;
    }
    __syncthreads();
    mfma_step(As + buf * TSZ, Bs + buf * TSZ, wm, wn, fr, g, acc);
}

__device__ __forceinline__ void gemm_loop_db64d(const unsigned short* Ag, int strideA,
                                                const unsigned short* Bg, int strideB, int Kk,
                                                unsigned short* As, unsigned short* Bs,
                                                int wave, int lane, int wm, int wn, int fr, int g,
                                                floatx4 acc[2][4], floatx4 accd[2], short8 bones) {
    __syncthreads();
    stage64x32(Ag, strideA, As, wave, lane);
    stage128x32(Bg, strideB, Bs, wave, lane);
    int buf = 0;
    for (int k0 = 32; k0 < Kk; k0 += 32) {
        __syncthreads();
        const int nb = buf ^ 1;
        stage64x32(Ag + k0, strideA, As + nb * TA64, wave, lane);
        stage128x32(Bg + k0, strideB, Bs + nb * TSZ, wave, lane);
        mfma_step64d(As + buf * TA64, Bs + buf * TSZ, wm, wn, fr, g, acc, accd, bones);
        buf = nb;
    }
    __syncthreads();
    mfma_step64d(As + buf * TA64, Bs + buf * TSZ, wm, wn, fr, g, acc, accd, bones);
}

__device__ __forceinline__ void gemm_loop_db64(const unsigned short* Ag, int strideA,
                                               const unsigned short* Bg, int strideB, int Kk,
                                               unsigned short* As, unsigned short* Bs,
                                               int wave, int lane, int wm, int wn, int fr, int g,
                                               floatx4 acc[2][4]) {
    __syncthreads();
    stage64x32(Ag, strideA, As, wave, lane);
    stage128x32(Bg, strideB, Bs, wave, lane);
    int buf = 0;
    for (int k0 = 32; k0 < Kk; k0 += 32) {
        __syncthreads();
        const int nb = buf ^ 1;
        stage64x32(Ag + k0, strideA, As + nb * TA64, wave, lane);
        stage128x32(Bg + k0, strideB, Bs + nb * TSZ, wave, lane);
        mfma_step64(As + buf * TA64, Bs + buf * TSZ, wm, wn, fr, g, acc);
        buf = nb;
    }
    __syncthreads();
    mfma_step64(As + buf * TA64, Bs + buf * TSZ, wm, wn, fr, g, acc);
}

// ---------------- prep: cvt h + cvt 4 weights + transpose memory ----------------
__global__ __launch_bounds__(256) void prep(const float* __restrict__ h,
                                            const float* __restrict__ w_q, const float* __restrict__ w_k,
                                            const float* __restrict__ w_v, const float* __restrict__ w_o,
                                            const float* __restrict__ memory,
                                            unsigned short* __restrict__ h_b,
                                            unsigned short* __restrict__ wq_b, unsigned short* __restrict__ wk_b,
                                            unsigned short* __restrict__ wv_b, unsigned short* __restrict__ wo_b,
                                            unsigned short* __restrict__ memT)
{
    __shared__ unsigned short T[64][72];
    const int id = blockIdx.x, tid = threadIdx.x;
    if (id < 4096) {
        const size_t i = ((size_t)id * 256 + tid) * 4;
        float4 v = *(const float4*)(h + i);
        ushort4 o; o.x = f2bf(v.x); o.y = f2bf(v.y); o.z = f2bf(v.z); o.w = f2bf(v.w);
        *(ushort4*)(h_b + i) = o;
    } else if (id < 8192) {
        const int t = id - 4096, which = t >> 10;
        const float* in = (which == 0) ? w_q : (which == 1) ? w_k : (which == 2) ? w_v : w_o;
        unsigned short* out = (which == 0) ? wq_b : (which == 1) ? wk_b : (which == 2) ? wv_b : wo_b;
        const size_t i = ((size_t)(t & 1023) * 256 + tid) * 4;
        float4 v = *(const float4*)(in + i);
        ushort4 o; o.x = f2bf(v.x); o.y = f2bf(v.y); o.z = f2bf(v.z); o.w = f2bf(v.w);
        *(ushort4*)(out + i) = o;
    } else {
        const int t = id - 8192;
        const int d0 = (t >> 4) * 64, e0 = (t & 15) * 64;
        const int r = tid >> 4, c4 = (tid & 15) * 4;
        for (int rr = r; rr < 64; rr += 16) {
            float4 v = *(const float4*)(memory + (size_t)(d0 + rr) * D + e0 + c4);
            T[rr][c4 + 0] = f2bf(v.x); T[rr][c4 + 1] = f2bf(v.y);
            T[rr][c4 + 2] = f2bf(v.z); T[rr][c4 + 3] = f2bf(v.w);
        }
        __syncthreads();
        for (int rr = r; rr < 64; rr += 16) {
            ushort4 o;
            o.x = T[c4 + 0][rr]; o.y = T[c4 + 1][rr];
            o.z = T[c4 + 2][rr]; o.w = T[c4 + 3][rr];
            *(ushort4*)(memT + (size_t)(e0 + rr) * D + d0 + c4) = o;
        }
    }
}

// ---------------- proj8: q/k/v projections, 256x256 tile, 8-wave deep pipeline (r5 verified) ----
__global__ __launch_bounds__(512, 2) void proj8(const unsigned short* __restrict__ h_b,
                                                const unsigned short* __restrict__ wq,
                                                const unsigned short* __restrict__ wk,
                                                const unsigned short* __restrict__ wv,
                                                unsigned short* __restrict__ sq,
                                                unsigned short* __restrict__ sk,
                                                unsigned short* __restrict__ v)
{
    extern __shared__ unsigned short sm[];   // 128 KB
    const int id = blockIdx.x;
    const int x = id & 7, y = id >> 3;       // y 0..23
    const int strip = x + 8 * (y % 6);       // 0..47
    const int nn = y / 6;                    // 0..3
    const int sub = strip >> 4, m = strip & 15;
    const int m0 = m * 256, n0 = nn * 256;
    const unsigned short* Ag = h_b + (size_t)m0 * D;
    const unsigned short* Bg = ((sub == 0) ? wq : (sub == 1) ? wk : wv) + (size_t)n0 * D;
    unsigned short* C = (sub == 0) ? sq : (sub == 1) ? sk : v;

    const int tid = threadIdx.x;
    const int w = tid >> 6, lane = tid & 63;
    const int wr = w >> 2, wc = w & 3;
    const int fr = lane & 15, gq = lane >> 4;

    floatx4 acc[8][4] = {};
    gemm256_8ph(Ag, Bg, sm, tid, acc);

    const int q4 = gq * 4;
#pragma unroll
    for (int i = 0; i < 8; ++i)
#pragma unroll
        for (int j = 0; j < 4; ++j) {
            const int col = n0 + wc * 64 + j * 16 + fr;
#pragma unroll
            for (int r = 0; r < 4; ++r) {
                const int row = m0 + wr * 128 + i * 16 + q4 + r;
                float val = acc[i][j][r];
                if (sub < 2) val = elu1(val);
                C[(size_t)row * D + col] = f2bf(val);
            }
        }
}

// ---------------- stage2n: memgemm(64) + scores(72) 256²-8phase heavy blocks,
// then v-transpose(1024) + rowscale(512) light blocks backfilling idle CUs.
__global__ __launch_bounds__(512, 2) void stage2n(const unsigned short* __restrict__ sq,
                                                  const unsigned short* __restrict__ sk,
                                                  const unsigned short* __restrict__ memT,
                                                  const unsigned short* __restrict__ v_b,
                                                  const float* __restrict__ mnorm,
                                                  const float* __restrict__ gate,
                                                  unsigned short* __restrict__ combm,
                                                  unsigned short* __restrict__ Sbuf2,
                                                  unsigned short* __restrict__ vT,
                                                  float* __restrict__ rowscale)
{
    extern __shared__ unsigned short sm[];   // 128 KB
    const int id = blockIdx.x, tid = threadIdx.x;

    if (id < 136) {
        // heavy: bijective XCD swizzle over 136 = 8*17
        const int wk = (id & 7) * 17 + (id >> 3);
        const int w = tid >> 6, lane = tid & 63;
        const int wr = w >> 2, wc = w & 3;
        const int fr = lane & 15, gq = lane >> 4;
        const int q4 = gq * 4;

        if (wk < 64) {
            // memgemm: combm = f2bf(sq @ memT^T)
            const int mt = wk >> 2, nt = wk & 3;
            const int m0 = mt * 256, n0 = nt * 256;
            floatx4 acc[8][4] = {};
            gemm256_8ph(sq + (size_t)m0 * D, memT + (size_t)n0 * D, sm, tid, acc);
#pragma unroll
            for (int i = 0; i < 8; ++i)
#pragma unroll
                for (int j = 0; j < 4; ++j) {
                    const int col = n0 + wc * 64 + j * 16 + fr;
#pragma unroll
                    for (int r = 0; r < 4; ++r)
                        combm[(size_t)(m0 + wr * 128 + i * 16 + q4 + r) * D + col]
                            = f2bf(acc[i][j][r]);
                }
        } else {
            // scores: chunk pair (b, c, jc), 256x256 tile, K=D; diag mask in epilogue
            const int w2 = wk - 64;
            const int b = w2 / 36, p = w2 % 36;
            int c = 0;
            while ((c + 1) * (c + 2) / 2 <= p) ++c;
            const int jc = p - c * (c + 1) / 2;
            floatx4 acc[8][4] = {};
            gemm256_8ph(sq + ((size_t)b * S + (size_t)c * CH) * D,
                        sk + ((size_t)b * S + (size_t)jc * CH) * D, sm, tid, acc);
            unsigned short* Srow0 = Sbuf2 + (size_t)(b * NCH + c) * CH * S + jc * CH;
            const bool diag = (jc == c);
#pragma unroll
            for (int i = 0; i < 8; ++i)
#pragma unroll
                for (int j = 0; j < 4; ++j) {
                    const int col = wc * 64 + j * 16 + fr;
#pragma unroll
                    for (int r = 0; r < 4; ++r) {
                        const int row = wr * 128 + i * 16 + q4 + r;
                        float val = acc[i][j][r];
                        if (diag && col > row) val = 0.f;
                        Srow0[(size_t)row * S + col] = f2bf(val);
                    }
                }
        }
    } else if (id < 136 + 1024) {
        // transpose v_b [b][s][d] -> vT [b][d][s], one 64x64 tile, 512 threads
        unsigned short (*T)[72] = (unsigned short(*)[72])sm;
        const int t = id - 136;
        const int b = t >> 9, rem = t & 511;
        const int s0 = (rem >> 4) * 64, d0 = (rem & 15) * 64;
        const int r = tid >> 4, c4 = (tid & 15) * 4;   // r: 0..31
        const unsigned short* ip = v_b + (size_t)b * S * D;
        for (int rr = r; rr < 64; rr += 32) {
            ushort4 vv = *(const ushort4*)(ip + (size_t)(s0 + rr) * D + d0 + c4);
            T[rr][c4 + 0] = vv.x; T[rr][c4 + 1] = vv.y; T[rr][c4 + 2] = vv.z; T[rr][c4 + 3] = vv.w;
        }
        __syncthreads();
        unsigned short* op = vT + (size_t)b * D * S;
        for (int rr = r; rr < 64; rr += 32) {
            ushort4 o;
            o.x = T[c4 + 0][rr]; o.y = T[c4 + 1][rr];
            o.z = T[c4 + 2][rr]; o.w = T[c4 + 3][rr];
            *(ushort4*)(op + (size_t)(d0 + rr) * S + s0 + c4) = o;
        }
    } else {
        // rowscale: 8 rows/block (one per wave), vectorized
        const int wave = tid >> 6, lane = tid & 63;
        const int row = (id - 136 - 1024) * 8 + wave;
        const unsigned short* sr = sq + (size_t)row * D;
        float dot = 0.f, msum = 0.f;
#pragma unroll
        for (int p = 0; p < 2; ++p) {
            const int d0 = p * 512 + lane * 8;
            short8 sv = *(const short8*)(sr + d0);
            float4 m0 = *(const float4*)(mnorm + d0);
            float4 m1 = *(const float4*)(mnorm + d0 + 4);
            dot += bf2f((unsigned short)sv[0]) * m0.x + bf2f((unsigned short)sv[1]) * m0.y
                 + bf2f((unsigned short)sv[2]) * m0.z + bf2f((unsigned short)sv[3]) * m0.w
                 + bf2f((unsigned short)sv[4]) * m1.x + bf2f((unsigned short)sv[5]) * m1.y
                 + bf2f((unsigned short)sv[6]) * m1.z + bf2f((unsigned short)sv[7]) * m1.w;
            msum += m0.x + m0.y + m0.z + m0.w + m1.x + m1.y + m1.z + m1.w;
        }
        dot = wave_reduce(dot);
        msum = wave_reduce(msum);
        if (lane == 0) {
            const float gg = sigmoidf_(gate[0]);
            const float active = (msum >= EPSF) ? 1.f : 0.f;
            rowscale[row] = gg * active / fmaxf(dot, EPSF);
        }
    }
}

// ---------------- fused q/k/v projections (r2 fallback, 128-tile) ----------------
__global__ __launch_bounds__(256) void proj_fused(const unsigned short* __restrict__ h_b,
                                                  const unsigned short* __restrict__ wq,
                                                  const unsigned short* __restrict__ wk,
                                                  const unsigned short* __restrict__ wv,
                                                  unsigned short* __restrict__ sq,
                                                  unsigned short* __restrict__ sk,
                                                  unsigned short* __restrict__ v)
{
    __shared__ unsigned short As[2 * TSZ], Bs[2 * TSZ];
    const int id = blockIdx.x;
    const int x = id & 7, y = id >> 3;
    const int strip = x + 8 * (y % 12);
    const int n     = y / 12;
    const int sub = strip >> 5, m = strip & 31;
    const int m0 = m * 128, n0 = n * 128;
    const unsigned short* B = (sub == 0) ? wq : (sub == 1) ? wk : wv;
    unsigned short* C = (sub == 0) ? sq : (sub == 1) ? sk : v;

    const int tid = threadIdx.x, wave = tid >> 6, lane = tid & 63;
    const int wm = (wave >> 1) * 64, wn = (wave & 1) * 64;
    const int fr = lane & 15, g = lane >> 4;
    const int q4 = g * 4;

    floatx4 acc[4][4] = {};
    gemm_loop_db(h_b + (size_t)m0 * D, D, B + (size_t)n0 * D, D, D,
                 As, Bs, wave, lane, wm, wn, fr, g, acc);

#pragma unroll
    for (int i = 0; i < 4; ++i)
#pragma unroll
        for (int j = 0; j < 4; ++j) {
            const int col = n0 + wn + j * 16 + fr;
#pragma unroll
            for (int r = 0; r < 4; ++r) {
                const int row = m0 + wm + i * 16 + q4 + r;
                float val = acc[i][j][r];
                if (sub < 2) val = elu1(val);
                C[(size_t)row * D + col] = f2bf(val);
            }
        }
}

// ---------------- stage2 (r2 fallback) ----------------
__global__ __launch_bounds__(256) void stage2(const unsigned short* __restrict__ sq,
                                              const unsigned short* __restrict__ sk,
                                              const unsigned short* __restrict__ memT,
                                              const unsigned short* __restrict__ v_b,
                                              const float* __restrict__ mnorm,
                                              const float* __restrict__ gate,
                                              unsigned short* __restrict__ combm,
                                              unsigned short* __restrict__ Sbuf2,
                                              unsigned short* __restrict__ vT,
                                              float* __restrict__ rowscale)
{
    __shared__ unsigned short As[2 * TSZ], Bs[2 * TSZ];
    const int id = blockIdx.x, tid = threadIdx.x;
    const int wave = tid >> 6, lane = tid & 63;
    const int wm = (wave >> 1) * 64, wn = (wave & 1) * 64;
    const int fr = lane & 15, g = lane >> 4;
    const int q4 = g * 4;

    if (id < 256) {
        const int x = id & 7, y = id >> 3;
        const int m0 = (x + 8 * (y & 3)) * 128;
        const int n0 = (y >> 2) * 128;
        floatx4 acc[4][4] = {};
        gemm_loop_db(sq + (size_t)m0 * D, D, memT + (size_t)n0 * D, D, D,
                     As, Bs, wave, lane, wm, wn, fr, g, acc);
#pragma unroll
        for (int i = 0; i < 4; ++i)
#pragma unroll
            for (int j = 0; j < 4; ++j) {
                const int col = n0 + wn + j * 16 + fr;
#pragma unroll
                for (int r = 0; r < 4; ++r)
                    combm[(size_t)(m0 + wm + i * 16 + q4 + r) * D + col] = f2bf(acc[i][j][r]);
            }
    } else if (id < 544) {
        const int t = id - 256;
        const int b = t / 144, rem = t % 144;
        const int p = rem >> 2, tt = rem & 3;
        const int it = tt >> 1, jt = tt & 1;
        int c = 0;
        while ((c + 1) * (c + 2) / 2 <= p) ++c;
        const int j = p - c * (c + 1) / 2;
        unsigned short* Srow0 = Sbuf2 + (size_t)(b * NCH + c) * CH * S;

        if (j == c && jt > it) {
            const int row = it * 128 + (tid >> 1);
            unsigned short* zp = Srow0 + (size_t)row * S + j * CH + jt * 128 + (tid & 1) * 64;
            uint4 z4 = make_uint4(0, 0, 0, 0);
#pragma unroll
            for (int i = 0; i < 8; ++i) *(uint4*)(zp + i * 8) = z4;
            return;
        }
        floatx4 acc[4][4] = {};
        gemm_loop_db(sq + ((size_t)b * S + (size_t)c * CH + it * 128) * D, D,
                     sk + ((size_t)b * S + (size_t)j * CH + jt * 128) * D, D, D,
                     As, Bs, wave, lane, wm, wn, fr, g, acc);
        const bool diag = (j == c && it == jt);
#pragma unroll
        for (int i = 0; i < 4; ++i)
#pragma unroll
            for (int jj = 0; jj < 4; ++jj) {
                const int col = jt * 128 + wn + jj * 16 + fr;
#pragma unroll
                for (int r = 0; r < 4; ++r) {
                    const int row = it * 128 + wm + i * 16 + q4 + r;
                    float val = acc[i][jj][r];
                    if (diag && col > row) val = 0.f;
                    Srow0[(size_t)row * S + j * CH + col] = f2bf(val);
                }
            }
    } else if (id < 1568) {
        unsigned short (*T)[72] = (unsigned short(*)[72])As;
        const int t = id - 544;
        const int b = t >> 9, rem = t & 511;
        const int s0 = (rem >> 4) * 64, d0 = (rem & 15) * 64;
        const int r = tid >> 4, c4 = (tid & 15) * 4;
        const unsigned short* ip = v_b + (size_t)b * S * D;
        for (int rr = r; rr < 64; rr += 16) {
            ushort4 vv = *(const ushort4*)(ip + (size_t)(s0 + rr) * D + d0 + c4);
            T[rr][c4 + 0] = vv.x; T[rr][c4 + 1] = vv.y; T[rr][c4 + 2] = vv.z; T[rr][c4 + 3] = vv.w;
        }
        __syncthreads();
        unsigned short* op = vT + (size_t)b * D * S;
        for (int rr = r; rr < 64; rr += 16) {
            ushort4 o;
            o.x = T[c4 + 0][rr]; o.y = T[c4 + 1][rr];
            o.z = T[c4 + 2][rr]; o.w = T[c4 + 3][rr];
            *(ushort4*)(op + (size_t)(d0 + rr) * S + s0 + c4) = o;
        }
    } else {
        const int row = (id - 1568) * 4 + wave;
        const unsigned short* sr = sq + (size_t)row * D;
        float dot = 0.f, msum = 0.f;
#pragma unroll
        for (int p = 0; p < 2; ++p) {
            const int d0 = p * 512 + lane * 8;
            short8 sv = *(const short8*)(sr + d0);
            float4 m0 = *(const float4*)(mnorm + d0);
            float4 m1 = *(const float4*)(mnorm + d0 + 4);
            dot += bf2f((unsigned short)sv[0]) * m0.x + bf2f((unsigned short)sv[1]) * m0.y
                 + bf2f((unsigned short)sv[2]) * m0.z + bf2f((unsigned short)sv[3]) * m0.w
                 + bf2f((unsigned short)sv[4]) * m1.x + bf2f((unsigned short)sv[5]) * m1.y
                 + bf2f((unsigned short)sv[6]) * m1.z + bf2f((unsigned short)sv[7]) * m1.w;
            msum += m0.x + m0.y + m0.z + m0.w + m1.x + m1.y + m1.z + m1.w;
        }
        dot = wave_reduce(dot);
        msum = wave_reduce(msum);
        if (lane == 0) {
            const float gg = sigmoidf_(gate[0]);
            const float active = (msum >= EPSF) ? 1.f : 0.f;
            rowscale[row] = gg * active / fmaxf(dot, EPSF);
        }
    }
}

// ---------------- pv ----------------
__global__ __launch_bounds__(256) void pv64(const unsigned short* __restrict__ Sbuf2,
                                            const unsigned short* __restrict__ vT,
                                            const float* __restrict__ rowscale,
                                            const float* __restrict__ gate,
                                            unsigned short* __restrict__ combm)
{
    __shared__ unsigned short As2[2 * TA64], Bs2[2 * TSZ];
    const int id = blockIdx.x, tid = threadIdx.x;
    const int wave = tid >> 6, lane = tid & 63;
    const int wm = (wave >> 1) * 32, wn = (wave & 1) * 64;
    const int fr = lane & 15, g = lane >> 4;
    const int q4 = g * 4;

    const int x = id & 7, y = id >> 3;
    const int g_ = x + 8 * (y & 7);
    const int e  = y >> 3;
    const int b = g_ >> 5;
    const int rem = g_ & 31;
    const int c = (NCH - 1) - (rem >> 2);
    const int i0 = (rem & 3) * 64, e0 = e * 128;

    const short one_bf = (short)0x3F80;
    short8 bones = {one_bf, one_bf, one_bf, one_bf, one_bf, one_bf, one_bf, one_bf};

    floatx4 acc[2][4] = {};
    floatx4 accd[2] = {};
    gemm_loop_db64d(Sbuf2 + ((size_t)(b * NCH + c) * CH + i0) * S, S,
                    vT + (size_t)b * D * S + (size_t)e0 * S, S, (c + 1) * CH,
                    As2, Bs2, wave, lane, wm, wn, fr, g, acc, accd, bones);

    const float gg = sigmoidf_(gate[0]);
    const float wloc = 1.f - gg;
#pragma unroll
    for (int i = 0; i < 2; ++i)
#pragma unroll
        for (int j = 0; j < 4; ++j) {
            const int col = e0 + wn + j * 16 + fr;
#pragma unroll
            for (int r = 0; r < 4; ++r) {
                const int li = i0 + wm + i * 16 + q4 + r;
                const int rg = b * S + c * CH + li;
                const float inv = wloc / fmaxf(accd[i][r], EPSF);
                const size_t idx = (size_t)rg * D + col;
                combm[idx] = f2bf(bf2f(combm[idx]) * rowscale[rg] + acc[i][j][r] * inv);
            }
        }
}

// ---------------- out-proj ----------------
__global__ __launch_bounds__(256) void outproj64(const unsigned short* __restrict__ A,
                                                 const unsigned short* __restrict__ wo,
                                                 float* __restrict__ out)
{
    __shared__ unsigned short As2[2 * TA64], Bs2[2 * TSZ];
    const int id = blockIdx.x, tid = threadIdx.x;
    const int wave = tid >> 6, lane = tid & 63;
    const int wm = (wave >> 1) * 32, wn = (wave & 1) * 64;
    const int fr = lane & 15, g = lane >> 4;
    const int q4 = g * 4;

    const int x = id & 7, y = id >> 3;
    const int m0 = (x + 8 * (y & 7)) * 64;
    const int n0 = (y >> 3) * 128;

    floatx4 acc[2][4] = {};
    gemm_loop_db64(A + (size_t)m0 * D, D, wo + (size_t)n0 * D, D, D,
                   As2, Bs2, wave, lane, wm, wn, fr, g, acc);

#pragma unroll
    for (int i = 0; i < 2; ++i)
#pragma unroll
        for (int j = 0; j < 4; ++j) {
            const int col = n0 + wn + j * 16 + fr;
#pragma unroll
            for (int r = 0; r < 4; ++r)
                out[(size_t)(m0 + wm + i * 16 + q4 + r) * D + col] = acc[i][j][r];
        }
}

extern "C" void kernel_launch(void* const* d_in, const int* in_sizes, int n_in,
                              void* d_out, int out_size, void* d_ws, size_t ws_size,
                              hipStream_t stream)
{
    const float* h      = (const float*)d_in[0];
    const float* w_q    = (const float*)d_in[1];
    const float* w_k    = (const float*)d_in[2];
    const float* w_v    = (const float*)d_in[3];
    const float* w_o    = (const float*)d_in[4];
    const float* gate   = (const float*)d_in[5];
    const float* memory = (const float*)d_in[6];
    const float* mnorm  = (const float*)d_in[7];
    float* out = (float*)d_out;

    unsigned short* h_b   = (unsigned short*)d_ws;               // M*D (8 MB)
    unsigned short* wq_b  = h_b + (size_t)M * D;                 // D*D
    unsigned short* wk_b  = wq_b + (size_t)D * D;                // D*D
    unsigned short* wv_b  = wk_b + (size_t)D * D;                // D*D
    unsigned short* wo_b  = wv_b + (size_t)D * D;                // D*D
    unsigned short* memT  = wo_b + (size_t)D * D;                // D*D (2 MB)
    unsigned short* sq_b  = memT + (size_t)D * D;                // M*D (8 MB)
    unsigned short* sk_b  = sq_b + (size_t)M * D;                // M*D (8 MB)
    unsigned short* v_b   = sk_b + (size_t)M * D;                // M*D (8 MB)
    unsigned short* vT    = v_b + (size_t)M * D;                 // M*D (8 MB)
    unsigned short* Sbuf2 = vT + (size_t)M * D;                  // Bv*NCH*CH*S (16.8 MB)
    unsigned short* combm = Sbuf2 + (size_t)Bv * NCH * CH * S;   // M*D (8 MB)
    float* rowscale = (float*)(combm + (size_t)M * D);           // M fp32

    dim3 blk(256);

    prep<<<8448, blk, 0, stream>>>(h, w_q, w_k, w_v, w_o, memory,
                                   h_b, wq_b, wk_b, wv_b, wo_b, memT);

    static const bool lds128_ok = [] {
        bool a = hipFuncSetAttribute(reinterpret_cast<const void*>(proj8),
                                     hipFuncAttributeMaxDynamicSharedMemorySize,
                                     131072) == hipSuccess;
        bool b = hipFuncSetAttribute(reinterpret_cast<const void*>(stage2n),
                                     hipFuncAttributeMaxDynamicSharedMemorySize,
                                     131072) == hipSuccess;
        return a && b;
    }();

    if (lds128_ok) {
        proj8<<<192, dim3(512), 131072, stream>>>(h_b, wq_b, wk_b, wv_b, sq_b, sk_b, v_b);
        stage2n<<<1672, dim3(512), 131072, stream>>>(sq_b, sk_b, memT, v_b, mnorm, gate,
                                                     combm, Sbuf2, vT, rowscale);
    } else {
        proj_fused<<<768, blk, 0, stream>>>(h_b, wq_b, wk_b, wv_b, sq_b, sk_b, v_b);
        stage2<<<2592, blk, 0, stream>>>(sq_b, sk_b, memT, v_b, mnorm, gate,
                                         combm, Sbuf2, vT, rowscale);
    }

    pv64<<<512, blk, 0, stream>>>(Sbuf2, vT, rowscale, gate, combm);
    outproj64<<<512, blk, 0, stream>>>(combm, wo_b, out);
}

// Round 7
// 204.172 us; speedup vs baseline: 1.2144x; 1.0696x over previous
//
#include <hip/hip_runtime.h>
#include <cstddef>

#define EPSF 1e-6f

constexpr int D   = 1024;
constexpr int Bv  = 2;
constexpr int S   = 2048;
constexpr int M   = Bv * S;    // 4096
constexpr int CH  = 256;       // chunk
constexpr int NCH = S / CH;    // 8

constexpr int TSZ  = 128 * 32; // 128-row LDS tile (elems, 8 KB)
constexpr int TA64 = 64 * 32;  // 64-row LDS tile (elems, 4 KB)
constexpr int T66  = 64 * 64;  // 64x64 BK=64 LDS tile (elems, 8 KB)

typedef __attribute__((ext_vector_type(8))) short short8;   // 8 bf16
typedef __attribute__((ext_vector_type(4))) float floatx4;  // 4 fp32

__device__ __forceinline__ float elu1(float x) { return x > 0.f ? x + 1.f : __expf(x); }
__device__ __forceinline__ float sigmoidf_(float x) { return 1.f / (1.f + __expf(-x)); }
__device__ __forceinline__ unsigned short f2bf(float x) {
    unsigned u = __float_as_uint(x);
    return (unsigned short)((u + 0x7fffu + ((u >> 16) & 1u)) >> 16);
}
__device__ __forceinline__ float bf2f(unsigned short h) {
    return __uint_as_float(((unsigned)h) << 16);
}
__device__ __forceinline__ float wave_reduce(float x) {
#pragma unroll
    for (int off = 32; off > 0; off >>= 1) x += __shfl_down(x, off);
    return x;
}

// async global->LDS, 16B per lane (dest = wave-uniform base + lane*16)
__device__ __forceinline__ void gl_lds16(const unsigned short* g, unsigned short* l) {
    __builtin_amdgcn_global_load_lds(
        (const __attribute__((address_space(1))) void*)g,
        (__attribute__((address_space(3))) void*)l, 16, 0, 0);
}

// ==================== 256x256 8-phase deep-pipeline core (r5 HW-verified) ====================
__device__ __forceinline__ void gemm256_8ph(const unsigned short* __restrict__ Ag,
                                            const unsigned short* __restrict__ Bg,
                                            unsigned short* sm, int tid,
                                            floatx4 acc[8][4]) {
    const int lane = tid & 63, w = tid >> 6;
    const int wr = w >> 2, wc = w & 3;       // 2M x 4N waves, per-wave 128x64 output
    const int fr = lane & 15, gq = lane >> 4;
    const int swz = fr & 7;

    const int r0 = tid >> 3;
    const int c0 = (tid & 7) ^ (r0 & 7);            // pre-swizzled source chunk
    const int r1 = (tid + 512) >> 3;
    const int c1 = ((tid + 512) & 7) ^ (r1 & 7);
    const size_t so0 = (size_t)r0 * D + (size_t)c0 * 8;
    const size_t so1 = (size_t)r1 * D + (size_t)c1 * 8;
    unsigned short* const dst0 = sm + tid * 8;
    unsigned short* const dst1 = sm + (tid + 512) * 8;

    auto STG = [&](int kt, int b, int which) {
        const unsigned short* Gs = ((which) < 2 ? Ag : Bg)
            + (size_t)(((which) & 1) * 128) * D + (size_t)(kt) * 64;
        const int slot = (((b) << 2) + (which)) << 13;
        gl_lds16(Gs + so0, dst0 + slot);
        gl_lds16(Gs + so1, dst1 + slot);
    };

    STG(0, 0, 0); STG(0, 0, 1); STG(0, 0, 2); STG(0, 0, 3);
    STG(1, 1, 2); STG(1, 1, 3);
    asm volatile("s_waitcnt vmcnt(4)" ::: "memory");
    __builtin_amdgcn_s_barrier();

    const int NT = D / 64;  // 16 K-tiles
    for (int u = 0; u < NT; ++u) {
        const int bu = u & 1;
        const unsigned short* Ah = sm + (((bu << 2) + wr) << 13);
        const unsigned short* Bh = sm + (((bu << 2) + 2 + (wc >> 1)) << 13);
        const int brow = (wc & 1) * 64;
        short8 bfr[4][2];
#pragma unroll
        for (int s = 0; s < 4; ++s) {
            short8 afr[2][2];
#pragma unroll
            for (int i2 = 0; i2 < 2; ++i2)
#pragma unroll
                for (int ks = 0; ks < 2; ++ks)
                    afr[i2][ks] = *(const short8*)&Ah[((s * 2 + i2) * 16 + fr) * 64
                                                      + ((((ks << 2) + gq) ^ swz) << 3)];
            if (s == 0) {
#pragma unroll
                for (int j = 0; j < 4; ++j)
#pragma unroll
                    for (int ks = 0; ks < 2; ++ks)
                        bfr[j][ks] = *(const short8*)&Bh[(brow + j * 16 + fr) * 64
                                                         + ((((ks << 2) + gq) ^ swz) << 3)];
            }
            if (s == 0)      { if (u + 1 < NT) STG(u + 1, bu ^ 1, 0); }
            else if (s == 1) { if (u + 1 < NT) STG(u + 1, bu ^ 1, 1); }
            else if (s == 2) { if (u + 2 < NT) STG(u + 2, bu, 2); }
            else {
                if (u + 2 < NT) {
                    STG(u + 2, bu, 3);
                    asm volatile("s_waitcnt vmcnt(4)" ::: "memory");
                } else if (u + 1 < NT) {
                    asm volatile("s_waitcnt vmcnt(0)" ::: "memory");
                }
            }
            __builtin_amdgcn_s_barrier();
            __builtin_amdgcn_s_setprio(1);
#pragma unroll
            for (int i2 = 0; i2 < 2; ++i2)
#pragma unroll
                for (int j = 0; j < 4; ++j)
#pragma unroll
                    for (int ks = 0; ks < 2; ++ks)
                        acc[s * 2 + i2][j] = __builtin_amdgcn_mfma_f32_16x16x32_bf16(
                            afr[i2][ks], bfr[j][ks], acc[s * 2 + i2][j], 0, 0, 0);
            __builtin_amdgcn_s_setprio(0);
            __builtin_amdgcn_s_barrier();
        }
    }
}

// ---- r2-proven 128-tile machinery (fallback path + heavy kernels) ----
__device__ __forceinline__ void stage128x32(const unsigned short* g, int stride,
                                            unsigned short* lds, int wave, int lane) {
    const int t   = (wave << 6) + lane;
    const int row = t >> 2;
    const int cb  = (((t & 3) ^ ((row >> 1) & 3)) << 3);
    unsigned short* l0 = lds + (wave << 9);
    gl_lds16(g + (size_t)row * stride + cb, l0);
    gl_lds16(g + (size_t)(row + 64) * stride + cb, l0 + 2048);
}

__device__ __forceinline__ void stage64x32(const unsigned short* g, int stride,
                                           unsigned short* lds, int wave, int lane) {
    const int t   = (wave << 6) + lane;
    const int row = t >> 2;
    const int cb  = (((t & 3) ^ ((row >> 1) & 3)) << 3);
    gl_lds16(g + (size_t)row * stride + cb, lds + (wave << 9));
}

// r1-verified BK=64 64-row staging: phys chunk p of row r holds logical c = p ^ (r&7)
__device__ __forceinline__ void stage64x64(const unsigned short* g, int stride,
                                           unsigned short* lds, int wave, int lane) {
    const int base = (wave << 6) + lane;
    const int c8   = (lane & 7) ^ (lane >> 3);
#pragma unroll
    for (int q = 0; q < 2; ++q) {
        const int P   = (q << 8) + base;
        const int row = P >> 3;
        gl_lds16(g + (size_t)row * stride + (c8 << 3), lds + (q << 11) + (wave << 9));
    }
}

__device__ __forceinline__ void mfma_step(const unsigned short* As, const unsigned short* Bs,
                                          int wm, int wn, int fr, int g, floatx4 acc[4][4]) {
    const int off = ((g ^ ((fr >> 1) & 3)) << 3);
    short8 af[4], bf[4];
#pragma unroll
    for (int i = 0; i < 4; ++i) af[i] = *(const short8*)&As[(wm + i * 16 + fr) * 32 + off];
#pragma unroll
    for (int j = 0; j < 4; ++j) bf[j] = *(const short8*)&Bs[(wn + j * 16 + fr) * 32 + off];
#pragma unroll
    for (int i = 0; i < 4; ++i)
#pragma unroll
        for (int j = 0; j < 4; ++j)
            acc[i][j] = __builtin_amdgcn_mfma_f32_16x16x32_bf16(af[i], bf[j], acc[i][j], 0, 0, 0);
}

// 64x64 tile, BK=64, with rowsum (r1-verified read swizzle: off = (g+4s)^ (fr&7))
__device__ __forceinline__ void mfma_6464d(const unsigned short* As, const unsigned short* Bs,
                                           int wm, int wn, int fr, int g,
                                           floatx4 acc[2][2], floatx4 accd[2], short8 bones) {
    const int x7 = fr & 7;
#pragma unroll
    for (int s = 0; s < 2; ++s) {
        const int off = ((g + 4 * s) ^ x7) << 3;
        short8 af[2], bf[2];
#pragma unroll
        for (int i = 0; i < 2; ++i) af[i] = *(const short8*)&As[(wm + i * 16 + fr) * 64 + off];
#pragma unroll
        for (int j = 0; j < 2; ++j) bf[j] = *(const short8*)&Bs[(wn + j * 16 + fr) * 64 + off];
#pragma unroll
        for (int i = 0; i < 2; ++i) {
#pragma unroll
            for (int j = 0; j < 2; ++j)
                acc[i][j] = __builtin_amdgcn_mfma_f32_16x16x32_bf16(af[i], bf[j], acc[i][j], 0, 0, 0);
            accd[i] = __builtin_amdgcn_mfma_f32_16x16x32_bf16(af[i], bones, accd[i], 0, 0, 0);
        }
    }
}

// 64x64 tile, BK=64, plain
__device__ __forceinline__ void mfma_6464(const unsigned short* As, const unsigned short* Bs,
                                          int wm, int wn, int fr, int g, floatx4 acc[2][2]) {
    const int x7 = fr & 7;
#pragma unroll
    for (int s = 0; s < 2; ++s) {
        const int off = ((g + 4 * s) ^ x7) << 3;
        short8 af[2], bf[2];
#pragma unroll
        for (int i = 0; i < 2; ++i) af[i] = *(const short8*)&As[(wm + i * 16 + fr) * 64 + off];
#pragma unroll
        for (int j = 0; j < 2; ++j) bf[j] = *(const short8*)&Bs[(wn + j * 16 + fr) * 64 + off];
#pragma unroll
        for (int i = 0; i < 2; ++i)
#pragma unroll
            for (int j = 0; j < 2; ++j)
                acc[i][j] = __builtin_amdgcn_mfma_f32_16x16x32_bf16(af[i], bf[j], acc[i][j], 0, 0, 0);
    }
}

__device__ __forceinline__ void gemm_loop_db(const unsigned short* Ag, int strideA,
                                             const unsigned short* Bg, int strideB, int Kk,
                                             unsigned short* As, unsigned short* Bs,
                                             int wave, int lane, int wm, int wn, int fr, int g,
                                             floatx4 acc[4][4]) {
    __syncthreads();
    stage128x32(Ag, strideA, As, wave, lane);
    stage128x32(Bg, strideB, Bs, wave, lane);
    int buf = 0;
    for (int k0 = 32; k0 < Kk; k0 += 32) {
        __syncthreads();
        const int nb = buf ^ 1;
        stage128x32(Ag + k0, strideA, As + nb * TSZ, wave, lane);
        stage128x32(Bg + k0, strideB, Bs + nb * TSZ, wave, lane);
        mfma_step(As + buf * TSZ, Bs + buf * TSZ, wm, wn, fr, g, acc);
        buf = nb;
    }
    __syncthreads();
    mfma_step(As + buf * TSZ, Bs + buf * TSZ, wm, wn, fr, g, acc);
}

// Double-buffered K-loop, 64x64 tile, BK=64, with in-register rowsum
__device__ __forceinline__ void gemm_loop_6464d(const unsigned short* Ag, int sA,
                                                const unsigned short* Bg, int sB, int Kk,
                                                unsigned short* As, unsigned short* Bs,
                                                int wave, int lane, int wm, int wn, int fr, int g,
                                                floatx4 acc[2][2], floatx4 accd[2], short8 bones) {
    __syncthreads();
    stage64x64(Ag, sA, As, wave, lane);
    stage64x64(Bg, sB, Bs, wave, lane);
    int buf = 0;
    for (int k0 = 64; k0 < Kk; k0 += 64) {
        __syncthreads();
        const int nb = buf ^ 1;
        stage64x64(Ag + k0, sA, As + nb * T66, wave, lane);
        stage64x64(Bg + k0, sB, Bs + nb * T66, wave, lane);
        mfma_6464d(As + buf * T66, Bs + buf * T66, wm, wn, fr, g, acc, accd, bones);
        buf = nb;
    }
    __syncthreads();
    mfma_6464d(As + buf * T66, Bs + buf * T66, wm, wn, fr, g, acc, accd, bones);
}

// Double-buffered K-loop, 64x64 tile, BK=64, plain
__device__ __forceinline__ void gemm_loop_6464(const unsigned short* Ag, int sA,
                                               const unsigned short* Bg, int sB, int Kk,
                                               unsigned short* As, unsigned short* Bs,
                                               int wave, int lane, int wm, int wn, int fr, int g,
                                               floatx4 acc[2][2]) {
    __syncthreads();
    stage64x64(Ag, sA, As, wave, lane);
    stage64x64(Bg, sB, Bs, wave, lane);
    int buf = 0;
    for (int k0 = 64; k0 < Kk; k0 += 64) {
        __syncthreads();
        const int nb = buf ^ 1;
        stage64x64(Ag + k0, sA, As + nb * T66, wave, lane);
        stage64x64(Bg + k0, sB, Bs + nb * T66, wave, lane);
        mfma_6464(As + buf * T66, Bs + buf * T66, wm, wn, fr, g, acc);
        buf = nb;
    }
    __syncthreads();
    mfma_6464(As + buf * T66, Bs + buf * T66, wm, wn, fr, g, acc);
}

// ---------------- prep: cvt h + cvt 4 weights + transpose memory ----------------
__global__ __launch_bounds__(256) void prep(const float* __restrict__ h,
                                            const float* __restrict__ w_q, const float* __restrict__ w_k,
                                            const float* __restrict__ w_v, const float* __restrict__ w_o,
                                            const float* __restrict__ memory,
                                            unsigned short* __restrict__ h_b,
                                            unsigned short* __restrict__ wq_b, unsigned short* __restrict__ wk_b,
                                            unsigned short* __restrict__ wv_b, unsigned short* __restrict__ wo_b,
                                            unsigned short* __restrict__ memT)
{
    __shared__ unsigned short T[64][72];
    const int id = blockIdx.x, tid = threadIdx.x;
    if (id < 4096) {
        const size_t i = ((size_t)id * 256 + tid) * 4;
        float4 v = *(const float4*)(h + i);
        ushort4 o; o.x = f2bf(v.x); o.y = f2bf(v.y); o.z = f2bf(v.z); o.w = f2bf(v.w);
        *(ushort4*)(h_b + i) = o;
    } else if (id < 8192) {
        const int t = id - 4096, which = t >> 10;
        const float* in = (which == 0) ? w_q : (which == 1) ? w_k : (which == 2) ? w_v : w_o;
        unsigned short* out = (which == 0) ? wq_b : (which == 1) ? wk_b : (which == 2) ? wv_b : wo_b;
        const size_t i = ((size_t)(t & 1023) * 256 + tid) * 4;
        float4 v = *(const float4*)(in + i);
        ushort4 o; o.x = f2bf(v.x); o.y = f2bf(v.y); o.z = f2bf(v.z); o.w = f2bf(v.w);
        *(ushort4*)(out + i) = o;
    } else {
        const int t = id - 8192;
        const int d0 = (t >> 4) * 64, e0 = (t & 15) * 64;
        const int r = tid >> 4, c4 = (tid & 15) * 4;
        for (int rr = r; rr < 64; rr += 16) {
            float4 v = *(const float4*)(memory + (size_t)(d0 + rr) * D + e0 + c4);
            T[rr][c4 + 0] = f2bf(v.x); T[rr][c4 + 1] = f2bf(v.y);
            T[rr][c4 + 2] = f2bf(v.z); T[rr][c4 + 3] = f2bf(v.w);
        }
        __syncthreads();
        for (int rr = r; rr < 64; rr += 16) {
            ushort4 o;
            o.x = T[c4 + 0][rr]; o.y = T[c4 + 1][rr];
            o.z = T[c4 + 2][rr]; o.w = T[c4 + 3][rr];
            *(ushort4*)(memT + (size_t)(e0 + rr) * D + d0 + c4) = o;
        }
    }
}

// ---------------- proj8: q/k/v projections, 256x256 tile, 8-wave deep pipeline (r5 verified) ----
__global__ __launch_bounds__(512, 2) void proj8(const unsigned short* __restrict__ h_b,
                                                const unsigned short* __restrict__ wq,
                                                const unsigned short* __restrict__ wk,
                                                const unsigned short* __restrict__ wv,
                                                unsigned short* __restrict__ sq,
                                                unsigned short* __restrict__ sk,
                                                unsigned short* __restrict__ v)
{
    extern __shared__ unsigned short sm[];   // 128 KB
    const int id = blockIdx.x;
    const int x = id & 7, y = id >> 3;       // y 0..23
    const int strip = x + 8 * (y % 6);       // 0..47
    const int nn = y / 6;                    // 0..3
    const int sub = strip >> 4, m = strip & 15;
    const int m0 = m * 256, n0 = nn * 256;
    const unsigned short* Ag = h_b + (size_t)m0 * D;
    const unsigned short* Bg = ((sub == 0) ? wq : (sub == 1) ? wk : wv) + (size_t)n0 * D;
    unsigned short* C = (sub == 0) ? sq : (sub == 1) ? sk : v;

    const int tid = threadIdx.x;
    const int w = tid >> 6, lane = tid & 63;
    const int wr = w >> 2, wc = w & 3;
    const int fr = lane & 15, gq = lane >> 4;

    floatx4 acc[8][4] = {};
    gemm256_8ph(Ag, Bg, sm, tid, acc);

    const int q4 = gq * 4;
#pragma unroll
    for (int i = 0; i < 8; ++i)
#pragma unroll
        for (int j = 0; j < 4; ++j) {
            const int col = n0 + wc * 64 + j * 16 + fr;
#pragma unroll
            for (int r = 0; r < 4; ++r) {
                const int row = m0 + wr * 128 + i * 16 + q4 + r;
                float val = acc[i][j][r];
                if (sub < 2) val = elu1(val);
                C[(size_t)row * D + col] = f2bf(val);
            }
        }
}

// ---------------- stage2n: memgemm(64) + scores(72) heavy + transpose/rowscale light (r6 verified)
__global__ __launch_bounds__(512, 2) void stage2n(const unsigned short* __restrict__ sq,
                                                  const unsigned short* __restrict__ sk,
                                                  const unsigned short* __restrict__ memT,
                                                  const unsigned short* __restrict__ v_b,
                                                  const float* __restrict__ mnorm,
                                                  const float* __restrict__ gate,
                                                  unsigned short* __restrict__ combm,
                                                  unsigned short* __restrict__ Sbuf2,
                                                  unsigned short* __restrict__ vT,
                                                  float* __restrict__ rowscale)
{
    extern __shared__ unsigned short sm[];   // 128 KB
    const int id = blockIdx.x, tid = threadIdx.x;

    if (id < 136) {
        const int wk = (id & 7) * 17 + (id >> 3);
        const int w = tid >> 6, lane = tid & 63;
        const int wr = w >> 2, wc = w & 3;
        const int fr = lane & 15, gq = lane >> 4;
        const int q4 = gq * 4;

        if (wk < 64) {
            const int mt = wk >> 2, nt = wk & 3;
            const int m0 = mt * 256, n0 = nt * 256;
            floatx4 acc[8][4] = {};
            gemm256_8ph(sq + (size_t)m0 * D, memT + (size_t)n0 * D, sm, tid, acc);
#pragma unroll
            for (int i = 0; i < 8; ++i)
#pragma unroll
                for (int j = 0; j < 4; ++j) {
                    const int col = n0 + wc * 64 + j * 16 + fr;
#pragma unroll
                    for (int r = 0; r < 4; ++r)
                        combm[(size_t)(m0 + wr * 128 + i * 16 + q4 + r) * D + col]
                            = f2bf(acc[i][j][r]);
                }
        } else {
            const int w2 = wk - 64;
            const int b = w2 / 36, p = w2 % 36;
            int c = 0;
            while ((c + 1) * (c + 2) / 2 <= p) ++c;
            const int jc = p - c * (c + 1) / 2;
            floatx4 acc[8][4] = {};
            gemm256_8ph(sq + ((size_t)b * S + (size_t)c * CH) * D,
                        sk + ((size_t)b * S + (size_t)jc * CH) * D, sm, tid, acc);
            unsigned short* Srow0 = Sbuf2 + (size_t)(b * NCH + c) * CH * S + jc * CH;
            const bool diag = (jc == c);
#pragma unroll
            for (int i = 0; i < 8; ++i)
#pragma unroll
                for (int j = 0; j < 4; ++j) {
                    const int col = wc * 64 + j * 16 + fr;
#pragma unroll
                    for (int r = 0; r < 4; ++r) {
                        const int row = wr * 128 + i * 16 + q4 + r;
                        float val = acc[i][j][r];
                        if (diag && col > row) val = 0.f;
                        Srow0[(size_t)row * S + col] = f2bf(val);
                    }
                }
        }
    } else if (id < 136 + 1024) {
        unsigned short (*T)[72] = (unsigned short(*)[72])sm;
        const int t = id - 136;
        const int b = t >> 9, rem = t & 511;
        const int s0 = (rem >> 4) * 64, d0 = (rem & 15) * 64;
        const int r = tid >> 4, c4 = (tid & 15) * 4;   // r: 0..31
        const unsigned short* ip = v_b + (size_t)b * S * D;
        for (int rr = r; rr < 64; rr += 32) {
            ushort4 vv = *(const ushort4*)(ip + (size_t)(s0 + rr) * D + d0 + c4);
            T[rr][c4 + 0] = vv.x; T[rr][c4 + 1] = vv.y; T[rr][c4 + 2] = vv.z; T[rr][c4 + 3] = vv.w;
        }
        __syncthreads();
        unsigned short* op = vT + (size_t)b * D * S;
        for (int rr = r; rr < 64; rr += 32) {
            ushort4 o;
            o.x = T[c4 + 0][rr]; o.y = T[c4 + 1][rr];
            o.z = T[c4 + 2][rr]; o.w = T[c4 + 3][rr];
            *(ushort4*)(op + (size_t)(d0 + rr) * S + s0 + c4) = o;
        }
    } else {
        const int wave = tid >> 6, lane = tid & 63;
        const int row = (id - 136 - 1024) * 8 + wave;
        const unsigned short* sr = sq + (size_t)row * D;
        float dot = 0.f, msum = 0.f;
#pragma unroll
        for (int p = 0; p < 2; ++p) {
            const int d0 = p * 512 + lane * 8;
            short8 sv = *(const short8*)(sr + d0);
            float4 m0 = *(const float4*)(mnorm + d0);
            float4 m1 = *(const float4*)(mnorm + d0 + 4);
            dot += bf2f((unsigned short)sv[0]) * m0.x + bf2f((unsigned short)sv[1]) * m0.y
                 + bf2f((unsigned short)sv[2]) * m0.z + bf2f((unsigned short)sv[3]) * m0.w
                 + bf2f((unsigned short)sv[4]) * m1.x + bf2f((unsigned short)sv[5]) * m1.y
                 + bf2f((unsigned short)sv[6]) * m1.z + bf2f((unsigned short)sv[7]) * m1.w;
            msum += m0.x + m0.y + m0.z + m0.w + m1.x + m1.y + m1.z + m1.w;
        }
        dot = wave_reduce(dot);
        msum = wave_reduce(msum);
        if (lane == 0) {
            const float gg = sigmoidf_(gate[0]);
            const float active = (msum >= EPSF) ? 1.f : 0.f;
            rowscale[row] = gg * active / fmaxf(dot, EPSF);
        }
    }
}

// ---------------- fused q/k/v projections (r2 fallback, 128-tile) ----------------
__global__ __launch_bounds__(256) void proj_fused(const unsigned short* __restrict__ h_b,
                                                  const unsigned short* __restrict__ wq,
                                                  const unsigned short* __restrict__ wk,
                                                  const unsigned short* __restrict__ wv,
                                                  unsigned short* __restrict__ sq,
                                                  unsigned short* __restrict__ sk,
                                                  unsigned short* __restrict__ v)
{
    __shared__ unsigned short As[2 * TSZ], Bs[2 * TSZ];
    const int id = blockIdx.x;
    const int x = id & 7, y = id >> 3;
    const int strip = x + 8 * (y % 12);
    const int n     = y / 12;
    const int sub = strip >> 5, m = strip & 31;
    const int m0 = m * 128, n0 = n * 128;
    const unsigned short* B = (sub == 0) ? wq : (sub == 1) ? wk : wv;
    unsigned short* C = (sub == 0) ? sq : (sub == 1) ? sk : v;

    const int tid = threadIdx.x, wave = tid >> 6, lane = tid & 63;
    const int wm = (wave >> 1) * 64, wn = (wave & 1) * 64;
    const int fr = lane & 15, g = lane >> 4;
    const int q4 = g * 4;

    floatx4 acc[4][4] = {};
    gemm_loop_db(h_b + (size_t)m0 * D, D, B + (size_t)n0 * D, D, D,
                 As, Bs, wave, lane, wm, wn, fr, g, acc);

#pragma unroll
    for (int i = 0; i < 4; ++i)
#pragma unroll
        for (int j = 0; j < 4; ++j) {
            const int col = n0 + wn + j * 16 + fr;
#pragma unroll
            for (int r = 0; r < 4; ++r) {
                const int row = m0 + wm + i * 16 + q4 + r;
                float val = acc[i][j][r];
                if (sub < 2) val = elu1(val);
                C[(size_t)row * D + col] = f2bf(val);
            }
        }
}

// ---------------- stage2 (r2 fallback) ----------------
__global__ __launch_bounds__(256) void stage2(const unsigned short* __restrict__ sq,
                                              const unsigned short* __restrict__ sk,
                                              const unsigned short* __restrict__ memT,
                                              const unsigned short* __restrict__ v_b,
                                              const float* __restrict__ mnorm,
                                              const float* __restrict__ gate,
                                              unsigned short* __restrict__ combm,
                                              unsigned short* __restrict__ Sbuf2,
                                              unsigned short* __restrict__ vT,
                                              float* __restrict__ rowscale)
{
    __shared__ unsigned short As[2 * TSZ], Bs[2 * TSZ];
    const int id = blockIdx.x, tid = threadIdx.x;
    const int wave = tid >> 6, lane = tid & 63;
    const int wm = (wave >> 1) * 64, wn = (wave & 1) * 64;
    const int fr = lane & 15, g = lane >> 4;
    const int q4 = g * 4;

    if (id < 256) {
        const int x = id & 7, y = id >> 3;
        const int m0 = (x + 8 * (y & 3)) * 128;
        const int n0 = (y >> 2) * 128;
        floatx4 acc[4][4] = {};
        gemm_loop_db(sq + (size_t)m0 * D, D, memT + (size_t)n0 * D, D, D,
                     As, Bs, wave, lane, wm, wn, fr, g, acc);
#pragma unroll
        for (int i = 0; i < 4; ++i)
#pragma unroll
            for (int j = 0; j < 4; ++j) {
                const int col = n0 + wn + j * 16 + fr;
#pragma unroll
                for (int r = 0; r < 4; ++r)
                    combm[(size_t)(m0 + wm + i * 16 + q4 + r) * D + col] = f2bf(acc[i][j][r]);
            }
    } else if (id < 544) {
        const int t = id - 256;
        const int b = t / 144, rem = t % 144;
        const int p = rem >> 2, tt = rem & 3;
        const int it = tt >> 1, jt = tt & 1;
        int c = 0;
        while ((c + 1) * (c + 2) / 2 <= p) ++c;
        const int j = p - c * (c + 1) / 2;
        unsigned short* Srow0 = Sbuf2 + (size_t)(b * NCH + c) * CH * S;

        if (j == c && jt > it) {
            const int row = it * 128 + (tid >> 1);
            unsigned short* zp = Srow0 + (size_t)row * S + j * CH + jt * 128 + (tid & 1) * 64;
            uint4 z4 = make_uint4(0, 0, 0, 0);
#pragma unroll
            for (int i = 0; i < 8; ++i) *(uint4*)(zp + i * 8) = z4;
            return;
        }
        floatx4 acc[4][4] = {};
        gemm_loop_db(sq + ((size_t)b * S + (size_t)c * CH + it * 128) * D, D,
                     sk + ((size_t)b * S + (size_t)j * CH + jt * 128) * D, D, D,
                     As, Bs, wave, lane, wm, wn, fr, g, acc);
        const bool diag = (j == c && it == jt);
#pragma unroll
        for (int i = 0; i < 4; ++i)
#pragma unroll
            for (int jj = 0; jj < 4; ++jj) {
                const int col = jt * 128 + wn + jj * 16 + fr;
#pragma unroll
                for (int r = 0; r < 4; ++r) {
                    const int row = it * 128 + wm + i * 16 + q4 + r;
                    float val = acc[i][jj][r];
                    if (diag && col > row) val = 0.f;
                    Srow0[(size_t)row * S + j * CH + col] = f2bf(val);
                }
            }
    } else if (id < 1568) {
        unsigned short (*T)[72] = (unsigned short(*)[72])As;
        const int t = id - 544;
        const int b = t >> 9, rem = t & 511;
        const int s0 = (rem >> 4) * 64, d0 = (rem & 15) * 64;
        const int r = tid >> 4, c4 = (tid & 15) * 4;
        const unsigned short* ip = v_b + (size_t)b * S * D;
        for (int rr = r; rr < 64; rr += 16) {
            ushort4 vv = *(const ushort4*)(ip + (size_t)(s0 + rr) * D + d0 + c4);
            T[rr][c4 + 0] = vv.x; T[rr][c4 + 1] = vv.y; T[rr][c4 + 2] = vv.z; T[rr][c4 + 3] = vv.w;
        }
        __syncthreads();
        unsigned short* op = vT + (size_t)b * D * S;
        for (int rr = r; rr < 64; rr += 16) {
            ushort4 o;
            o.x = T[c4 + 0][rr]; o.y = T[c4 + 1][rr];
            o.z = T[c4 + 2][rr]; o.w = T[c4 + 3][rr];
            *(ushort4*)(op + (size_t)(d0 + rr) * S + s0 + c4) = o;
        }
    } else {
        const int row = (id - 1568) * 4 + wave;
        const unsigned short* sr = sq + (size_t)row * D;
        float dot = 0.f, msum = 0.f;
#pragma unroll
        for (int p = 0; p < 2; ++p) {
            const int d0 = p * 512 + lane * 8;
            short8 sv = *(const short8*)(sr + d0);
            float4 m0 = *(const float4*)(mnorm + d0);
            float4 m1 = *(const float4*)(mnorm + d0 + 4);
            dot += bf2f((unsigned short)sv[0]) * m0.x + bf2f((unsigned short)sv[1]) * m0.y
                 + bf2f((unsigned short)sv[2]) * m0.z + bf2f((unsigned short)sv[3]) * m0.w
                 + bf2f((unsigned short)sv[4]) * m1.x + bf2f((unsigned short)sv[5]) * m1.y
                 + bf2f((unsigned short)sv[6]) * m1.z + bf2f((unsigned short)sv[7]) * m1.w;
            msum += m0.x + m0.y + m0.z + m0.w + m1.x + m1.y + m1.z + m1.w;
        }
        dot = wave_reduce(dot);
        msum = wave_reduce(msum);
        if (lane == 0) {
            const float gg = sigmoidf_(gate[0]);
            const float active = (msum >= EPSF) ? 1.f : 0.f;
            rowscale[row] = gg * active / fmaxf(dot, EPSF);
        }
    }
}

// ---------------- pv: 64x64 tiles, BK=64, grid 1024 (r7: 4 blocks/CU TLP) ----------------
__global__ __launch_bounds__(256) void pv64(const unsigned short* __restrict__ Sbuf2,
                                            const unsigned short* __restrict__ vT,
                                            const float* __restrict__ rowscale,
                                            const float* __restrict__ gate,
                                            unsigned short* __restrict__ combm)
{
    __shared__ unsigned short As2[2 * T66], Bs2[2 * T66];   // 32 KB
    const int id = blockIdx.x, tid = threadIdx.x;
    const int wave = tid >> 6, lane = tid & 63;
    const int wm = (wave >> 1) * 32, wn = (wave & 1) * 32;
    const int fr = lane & 15, g = lane >> 4;
    const int q4 = g * 4;

    const int x = id & 7, y = id >> 3;          // y: 0..127
    const int g_ = x + 8 * (y & 7);             // group 0..63 = (b, c-rev, i) — XCD-colocated
    const int e  = y >> 3;                      // 0..15
    const int b = g_ >> 5;
    const int rem = g_ & 31;
    const int c = (NCH - 1) - (rem >> 2);       // long-K groups first within XCD
    const int i0 = (rem & 3) * 64, e0 = e * 64;

    const short one_bf = (short)0x3F80;
    short8 bones = {one_bf, one_bf, one_bf, one_bf, one_bf, one_bf, one_bf, one_bf};

    floatx4 acc[2][2] = {};
    floatx4 accd[2] = {};
    gemm_loop_6464d(Sbuf2 + ((size_t)(b * NCH + c) * CH + i0) * S, S,
                    vT + (size_t)b * D * S + (size_t)e0 * S, S, (c + 1) * CH,
                    As2, Bs2, wave, lane, wm, wn, fr, g, acc, accd, bones);

    const float gg = sigmoidf_(gate[0]);
    const float wloc = 1.f - gg;
#pragma unroll
    for (int i = 0; i < 2; ++i)
#pragma unroll
        for (int j = 0; j < 2; ++j) {
            const int col = e0 + wn + j * 16 + fr;
#pragma unroll
            for (int r = 0; r < 4; ++r) {
                const int li = i0 + wm + i * 16 + q4 + r;
                const int rg = b * S + c * CH + li;
                const float inv = wloc / fmaxf(accd[i][r], EPSF);
                const size_t idx = (size_t)rg * D + col;
                combm[idx] = f2bf(bf2f(combm[idx]) * rowscale[rg] + acc[i][j][r] * inv);
            }
        }
}

// ---------------- out-proj: 64x64 tiles, BK=64, grid 1024 ----------------
__global__ __launch_bounds__(256) void outproj64(const unsigned short* __restrict__ A,
                                                 const unsigned short* __restrict__ wo,
                                                 float* __restrict__ out)
{
    __shared__ unsigned short As2[2 * T66], Bs2[2 * T66];   // 32 KB
    const int id = blockIdx.x, tid = threadIdx.x;
    const int wave = tid >> 6, lane = tid & 63;
    const int wm = (wave >> 1) * 32, wn = (wave & 1) * 32;
    const int fr = lane & 15, g = lane >> 4;
    const int q4 = g * 4;

    const int x = id & 7, y = id >> 3;          // y: 0..127
    const int m0 = (x + 8 * (y & 7)) * 64;      // strip 0..63 — XCD-colocated
    const int n0 = (y >> 3) * 64;               // 0..15

    floatx4 acc[2][2] = {};
    gemm_loop_6464(A + (size_t)m0 * D, D, wo + (size_t)n0 * D, D, D,
                   As2, Bs2, wave, lane, wm, wn, fr, g, acc);

#pragma unroll
    for (int i = 0; i < 2; ++i)
#pragma unroll
        for (int j = 0; j < 2; ++j) {
            const int col = n0 + wn + j * 16 + fr;
#pragma unroll
            for (int r = 0; r < 4; ++r)
                out[(size_t)(m0 + wm + i * 16 + q4 + r) * D + col] = acc[i][j][r];
        }
}

extern "C" void kernel_launch(void* const* d_in, const int* in_sizes, int n_in,
                              void* d_out, int out_size, void* d_ws, size_t ws_size,
                              hipStream_t stream)
{
    const float* h      = (const float*)d_in[0];
    const float* w_q    = (const float*)d_in[1];
    const float* w_k    = (const float*)d_in[2];
    const float* w_v    = (const float*)d_in[3];
    const float* w_o    = (const float*)d_in[4];
    const float* gate   = (const float*)d_in[5];
    const float* memory = (const float*)d_in[6];
    const float* mnorm  = (const float*)d_in[7];
    float* out = (float*)d_out;

    unsigned short* h_b   = (unsigned short*)d_ws;               // M*D (8 MB)
    unsigned short* wq_b  = h_b + (size_t)M * D;                 // D*D
    unsigned short* wk_b  = wq_b + (size_t)D * D;                // D*D
    unsigned short* wv_b  = wk_b + (size_t)D * D;                // D*D
    unsigned short* wo_b  = wv_b + (size_t)D * D;                // D*D
    unsigned short* memT  = wo_b + (size_t)D * D;                // D*D (2 MB)
    unsigned short* sq_b  = memT + (size_t)D * D;                // M*D (8 MB)
    unsigned short* sk_b  = sq_b + (size_t)M * D;                // M*D (8 MB)
    unsigned short* v_b   = sk_b + (size_t)M * D;                // M*D (8 MB)
    unsigned short* vT    = v_b + (size_t)M * D;                 // M*D (8 MB)
    unsigned short* Sbuf2 = vT + (size_t)M * D;                  // Bv*NCH*CH*S (16.8 MB)
    unsigned short* combm = Sbuf2 + (size_t)Bv * NCH * CH * S;   // M*D (8 MB)
    float* rowscale = (float*)(combm + (size_t)M * D);           // M fp32

    dim3 blk(256);

    prep<<<8448, blk, 0, stream>>>(h, w_q, w_k, w_v, w_o, memory,
                                   h_b, wq_b, wk_b, wv_b, wo_b, memT);

    static const bool lds128_ok = [] {
        bool a = hipFuncSetAttribute(reinterpret_cast<const void*>(proj8),
                                     hipFuncAttributeMaxDynamicSharedMemorySize,
                                     131072) == hipSuccess;
        bool b = hipFuncSetAttribute(reinterpret_cast<const void*>(stage2n),
                                     hipFuncAttributeMaxDynamicSharedMemorySize,
                                     131072) == hipSuccess;
        return a && b;
    }();

    if (lds128_ok) {
        proj8<<<192, dim3(512), 131072, stream>>>(h_b, wq_b, wk_b, wv_b, sq_b, sk_b, v_b);
        stage2n<<<1672, dim3(512), 131072, stream>>>(sq_b, sk_b, memT, v_b, mnorm, gate,
                                                     combm, Sbuf2, vT, rowscale);
    } else {
        proj_fused<<<768, blk, 0, stream>>>(h_b, wq_b, wk_b, wv_b, sq_b, sk_b, v_b);
        stage2<<<2592, blk, 0, stream>>>(sq_b, sk_b, memT, v_b, mnorm, gate,
                                         combm, Sbuf2, vT, rowscale);
    }

    pv64<<<1024, blk, 0, stream>>>(Sbuf2, vT, rowscale, gate, combm);
    outproj64<<<1024, blk, 0, stream>>>(combm, wo_b, out);
}